// Round 2
// baseline (912.312 us; speedup 1.0000x reference)
//
#include <hip/hip_runtime.h>
#include <hip/hip_fp16.h>

typedef _Float16 f16;
typedef _Float16 half8 __attribute__((ext_vector_type(8)));
typedef _Float16 half4v __attribute__((ext_vector_type(4)));
typedef float f32x4 __attribute__((ext_vector_type(4)));

#define AS1(p) ((const __attribute__((address_space(1))) void*)(p))
#define AS3(p) ((__attribute__((address_space(3))) void*)(p))

__device__ __forceinline__ void gload_lds16(const void* g, void* l) {
    __builtin_amdgcn_global_load_lds(AS1(g), AS3(l), 16, 0, 0);
}

// ---------------------------------------------------------------------------
// f32 -> f16 conversion (vectorized x4)
// ---------------------------------------------------------------------------
__global__ __launch_bounds__(256) void cvt_f16_k(const float* __restrict__ in,
                                                 f16* __restrict__ out, int n4) {
    int i = blockIdx.x * 256 + threadIdx.x;
    if (i < n4) {
        float4 v = ((const float4*)in)[i];
        half4v o;
        o[0] = (f16)v.x; o[1] = (f16)v.y; o[2] = (f16)v.z; o[3] = (f16)v.w;
        ((half4v*)out)[i] = o;
    }
}

// ---------------------------------------------------------------------------
// GEMM: C[M,N] = A[M,K(lda)] * B[N,K]^T   (m97 structure, f16 MFMA 16x16x32)
// 128x128 tile, BK=64, 4 waves, 2x2 wave grid, 4x4 frags/wave
// ---------------------------------------------------------------------------
template <typename OutT>
__global__ __launch_bounds__(256, 2)
void gemm_tn(const f16* __restrict__ A, const f16* __restrict__ B,
             OutT* __restrict__ C, int M, int N, int K, int lda, int ldc) {
    __shared__ f16 As[128 * 64];
    __shared__ f16 Bs[128 * 64];

    int nTn = N >> 7;
    unsigned bid = blockIdx.x;
    unsigned cpx = gridDim.x >> 3;           // grid divisible by 8 (XCD swizzle)
    bid = (bid & 7u) * cpx + (bid >> 3);
    int bm = (int)(bid / nTn) * 128;
    int bn = (int)(bid % nTn) * 128;

    int tid = threadIdx.x;
    int wave = tid >> 6;
    int lane = tid & 63;
    int srow = lane >> 3;          // 0..7 (row within 8-row slot)
    int scol = (lane & 7) * 8;     // half offset within row

    int lr = lane & 15;
    int lkh = (lane >> 4) * 8;     // k offset (halfs) within 32

    f32x4 acc[4][4];
#pragma unroll
    for (int i = 0; i < 4; ++i)
#pragma unroll
        for (int j = 0; j < 4; ++j) acc[i][j] = (f32x4){0.f, 0.f, 0.f, 0.f};

    int wm = (wave >> 1) * 64;
    int wn = (wave & 1) * 64;

    for (int k0 = 0; k0 < K; k0 += 64) {
        __syncthreads();  // previous tile fully consumed
#pragma unroll
        for (int i = 0; i < 4; ++i) {
            int slot = wave * 4 + i;
            int row = slot * 8 + srow;
            gload_lds16(A + (size_t)(bm + row) * lda + (k0 + scol), As + slot * 512);
            gload_lds16(B + (size_t)(bn + row) * (size_t)K + (k0 + scol), Bs + slot * 512);
        }
        asm volatile("s_waitcnt vmcnt(0)" ::: "memory");
        __syncthreads();
#pragma unroll
        for (int kk = 0; kk < 2; ++kk) {
            half8 a[4], b[4];
#pragma unroll
            for (int mi = 0; mi < 4; ++mi)
                a[mi] = *(const half8*)(As + (wm + mi * 16 + lr) * 64 + kk * 32 + lkh);
#pragma unroll
            for (int nj = 0; nj < 4; ++nj)
                b[nj] = *(const half8*)(Bs + (wn + nj * 16 + lr) * 64 + kk * 32 + lkh);
#pragma unroll
            for (int mi = 0; mi < 4; ++mi)
#pragma unroll
                for (int nj = 0; nj < 4; ++nj)
                    acc[mi][nj] = __builtin_amdgcn_mfma_f32_16x16x32_f16(
                        a[mi], b[nj], acc[mi][nj], 0, 0, 0);
        }
    }

    int orow0 = bm + wm + (lane >> 4) * 4;
    int ocol0 = bn + wn + lr;
#pragma unroll
    for (int mi = 0; mi < 4; ++mi)
#pragma unroll
        for (int nj = 0; nj < 4; ++nj)
#pragma unroll
            for (int r = 0; r < 4; ++r)
                C[(size_t)(orow0 + mi * 16 + r) * ldc + (ocol0 + nj * 16)] =
                    (OutT)acc[mi][nj][r];
}

// ---------------------------------------------------------------------------
// Depthwise causal conv (k=4) + bias + SiLU.  One block per row m, 8 d/thread.
// ---------------------------------------------------------------------------
__global__ __launch_bounds__(256)
void conv_silu_k(const f16* __restrict__ xz, const float* __restrict__ cw,
                 const float* __restrict__ cb, f16* __restrict__ xc) {
    int m = blockIdx.x;          // 0..16383
    int d0 = threadIdx.x << 3;   // 0..2040
    int l = m & 4095;

    const float4* cw4 = (const float4*)cw;
    float4 w[8];
    float acc[8];
#pragma unroll
    for (int e = 0; e < 8; ++e) {
        w[e] = cw4[d0 + e];
        acc[e] = cb[d0 + e];
    }
#pragma unroll
    for (int j = 0; j < 4; ++j) {
        if (l - 3 + j >= 0) {
            half8 xv = *(const half8*)(xz + (size_t)(m - 3 + j) * 4096 + d0);
#pragma unroll
            for (int e = 0; e < 8; ++e) {
                float wj = (j == 0) ? w[e].x : (j == 1) ? w[e].y : (j == 2) ? w[e].z : w[e].w;
                acc[e] = fmaf((float)xv[e], wj, acc[e]);
            }
        }
    }
    half8 out = {};
#pragma unroll
    for (int e = 0; e < 8; ++e) {
        float v = acc[e];
        out[e] = (f16)(v / (1.f + expf(-v)));
    }
    *(half8*)(xc + (size_t)m * 2048 + d0) = out;
}

// ---------------------------------------------------------------------------
// x_dbl[m, 0..32] = x_conv[m,:] . x_proj_w[e,:]   (N=33, VALU)
// block = 64 rows x 4 k-slices (one slice per wave), LDS cross-wave reduce
// ---------------------------------------------------------------------------
__global__ __launch_bounds__(256)
void xdbl_k(const f16* __restrict__ xc, const float* __restrict__ W,
            float* __restrict__ xdbl) {
    __shared__ float lacc[4][64][33];
    int tid = threadIdx.x;
    int lane = tid & 63;
    int q = __builtin_amdgcn_readfirstlane(tid >> 6);  // wave-uniform k-slice
    int brow = blockIdx.x * 64;
    int m = brow + lane;
    int kb = q * 512;

    float acc[33];
#pragma unroll
    for (int e = 0; e < 33; ++e) acc[e] = 0.f;

    for (int k = 0; k < 512; k += 8) {
        half8 xv = *(const half8*)(xc + (size_t)m * 2048 + kb + k);
        float xf[8];
#pragma unroll
        for (int j = 0; j < 8; ++j) xf[j] = (float)xv[j];
#pragma unroll
        for (int e = 0; e < 33; ++e) {
            const float* wr = W + (size_t)e * 2048 + kb + k;
#pragma unroll
            for (int j = 0; j < 8; ++j) acc[e] = fmaf(xf[j], wr[j], acc[e]);
        }
    }
#pragma unroll
    for (int e = 0; e < 33; ++e) lacc[q][lane][e] = acc[e];
    __syncthreads();
    for (int idx = tid; idx < 64 * 33; idx += 256) {
        int r = idx / 33, e = idx - r * 33;
        float s = lacc[0][r][e] + lacc[1][r][e] + lacc[2][r][e] + lacc[3][r][e];
        xdbl[(size_t)(brow + r) * 33 + e] = s;
    }
}

// ---------------------------------------------------------------------------
// SP[m][48] = { dA[16]=exp(A_n*delta), dB[16]=delta*B, C[16] }, delta out
// ---------------------------------------------------------------------------
__global__ __launch_bounds__(256)
void sp_build_k(const float* __restrict__ xdbl, const float* __restrict__ A_log,
                float* __restrict__ SP, float* __restrict__ dlt) {
    int m = blockIdx.x * 256 + threadIdx.x;
    const float* row = xdbl + (size_t)m * 33;
    float v0 = row[0];
    float d = (v0 > 15.f) ? v0 : logf(1.f + expf(v0));  // softplus
    dlt[m] = d;
    float* sp = SP + (size_t)m * 48;
#pragma unroll
    for (int n = 0; n < 16; ++n) {
        float An = -expf(A_log[n]);
        sp[n] = expf(An * d);
        sp[16 + n] = d * row[1 + n];
        sp[32 + n] = row[17 + n];
    }
}

// ---------------------------------------------------------------------------
// G[bc][n] = exp(A_n * sum_{t in chunk} delta)   (chunk transition scalars)
// ---------------------------------------------------------------------------
__global__ __launch_bounds__(256)
void g_build_k(const float* __restrict__ dlt, const float* __restrict__ A_log,
               float* __restrict__ G) {
    __shared__ float red[256];
    int bc = blockIdx.x, t = threadIdx.x;
    red[t] = dlt[bc * 256 + t];
    __syncthreads();
#pragma unroll
    for (int s = 128; s > 0; s >>= 1) {
        if (t < s) red[t] += red[t + s];
        __syncthreads();
    }
    if (t < 16) G[bc * 16 + t] = expf(-expf(A_log[t]) * red[0]);
}

// ---------------------------------------------------------------------------
// Scan pass 1: per (b,c,d) local scan with h0=0; write final state F.
// blk = (bc*8 + dg); chunk T=256; SP chunk staged in LDS.
// ---------------------------------------------------------------------------
__global__ __launch_bounds__(256)
void scan1_k(const f16* __restrict__ xc, const float* __restrict__ SP,
             float* __restrict__ F) {
    __shared__ float sp[256 * 48];
    int blk = blockIdx.x;
    int dg = blk & 7;
    int bc = blk >> 3;
    int tid = threadIdx.x;
    int wave = tid >> 6;
    int d = dg * 256 + tid;
    int mbase = bc * 256;

    const char* spb = (const char*)(SP + (size_t)mbase * 48);
#pragma unroll
    for (int i = 0; i < 12; ++i)
        gload_lds16(spb + (size_t)(i * 256 + tid) * 16,
                    (char*)sp + (size_t)(i * 256 + wave * 64) * 16);
    asm volatile("s_waitcnt vmcnt(0)" ::: "memory");
    __syncthreads();

    float h[16];
#pragma unroll
    for (int n = 0; n < 16; ++n) h[n] = 0.f;

#pragma unroll 2
    for (int tt = 0; tt < 256; ++tt) {
        const float* r = sp + tt * 48;
        float x = (float)xc[(size_t)(mbase + tt) * 2048 + d];
#pragma unroll
        for (int n = 0; n < 16; ++n) h[n] = fmaf(h[n], r[n], x * r[16 + n]);
    }
    size_t fb = ((size_t)bc * 2048 + d) * 16;
#pragma unroll
    for (int n = 0; n < 16; ++n) F[fb + n] = h[n];
}

// ---------------------------------------------------------------------------
// Combine: sequential over 16 chunks per (b,d) chain: H0[c]=state before c.
// ---------------------------------------------------------------------------
__global__ __launch_bounds__(256)
void combine_k(const float* __restrict__ F, const float* __restrict__ G,
               float* __restrict__ H0) {
    int gid = blockIdx.x * 256 + threadIdx.x;  // 8192 chains
    int b = gid >> 11;
    int d = gid & 2047;
    float h[16];
#pragma unroll
    for (int n = 0; n < 16; ++n) h[n] = 0.f;
    for (int c = 0; c < 16; ++c) {
        int bc = b * 16 + c;
        size_t base = ((size_t)bc * 2048 + d) * 16;
#pragma unroll
        for (int n = 0; n < 16; ++n) H0[base + n] = h[n];
#pragma unroll
        for (int n = 0; n < 16; ++n) h[n] = fmaf(G[bc * 16 + n], h[n], F[base + n]);
    }
}

// ---------------------------------------------------------------------------
// Scan pass 2: replay with correct h0, emit y = (scan_y + x*D) * silu(z).
// y written into dead x_inner columns of xz buffer (cols 0..2047).
// ---------------------------------------------------------------------------
__global__ __launch_bounds__(256)
void scan2_k(const f16* __restrict__ xc, const f16* xz, const float* __restrict__ SP,
             const float* __restrict__ H0, const float* __restrict__ Dv,
             f16* yout) {
    __shared__ float sp[256 * 48];
    int blk = blockIdx.x;
    int dg = blk & 7;
    int bc = blk >> 3;
    int tid = threadIdx.x;
    int wave = tid >> 6;
    int d = dg * 256 + tid;
    int mbase = bc * 256;

    const char* spb = (const char*)(SP + (size_t)mbase * 48);
#pragma unroll
    for (int i = 0; i < 12; ++i)
        gload_lds16(spb + (size_t)(i * 256 + tid) * 16,
                    (char*)sp + (size_t)(i * 256 + wave * 64) * 16);
    asm volatile("s_waitcnt vmcnt(0)" ::: "memory");
    __syncthreads();

    size_t fb = ((size_t)bc * 2048 + d) * 16;
    float h[16];
#pragma unroll
    for (int n = 0; n < 16; ++n) h[n] = H0[fb + n];
    float Dd = Dv[d];

#pragma unroll 2
    for (int tt = 0; tt < 256; ++tt) {
        const float* r = sp + tt * 48;
        size_t mrow = (size_t)(mbase + tt);
        float x = (float)xc[mrow * 2048 + d];
        float z = (float)xz[mrow * 4096 + 2048 + d];
        float y0 = 0.f, y1 = 0.f, y2 = 0.f, y3 = 0.f;
#pragma unroll
        for (int n = 0; n < 16; n += 4) {
            h[n]     = fmaf(h[n],     r[n],     x * r[16 + n]);
            h[n + 1] = fmaf(h[n + 1], r[n + 1], x * r[17 + n]);
            h[n + 2] = fmaf(h[n + 2], r[n + 2], x * r[18 + n]);
            h[n + 3] = fmaf(h[n + 3], r[n + 3], x * r[19 + n]);
            y0 = fmaf(h[n],     r[32 + n], y0);
            y1 = fmaf(h[n + 1], r[33 + n], y1);
            y2 = fmaf(h[n + 2], r[34 + n], y2);
            y3 = fmaf(h[n + 3], r[35 + n], y3);
        }
        float y = (y0 + y1) + (y2 + y3);
        float yf = fmaf(x, Dd, y);
        float sz = z / (1.f + expf(-z));
        yout[mrow * 4096 + d] = (f16)(yf * sz);
    }
}

// ---------------------------------------------------------------------------
// Workspace layout (aliased by lifetime; peak 223,481,856 B ~= 213 MiB):
//   [0,   134217728)  xzh  : f16 16384x4096 (x_inner|z; x_inner cols become y)
//   [134217728, +67108864) region1:
//        phase A (cvt+GEMM1):  xh f16 16384x1024 @ +0, wih f16 4096x1024 @ +33554432
//        phase B (conv..scan2): xch f16 16384x2048 @ +0
//        phase C (final GEMM):  woh f16 1024x2048 @ +0  (converted after scan2)
//   [201326592, ...)  xdbl(2162688) dlt(65536) SP(3145728) G(4096) F(8388608) H0(8388608)
// ---------------------------------------------------------------------------
extern "C" void kernel_launch(void* const* d_in, const int* in_sizes, int n_in,
                              void* d_out, int out_size, void* d_ws, size_t ws_size,
                              hipStream_t stream) {
    const float* x      = (const float*)d_in[0];
    const float* w_in   = (const float*)d_in[1];
    const float* conv_w = (const float*)d_in[2];
    const float* conv_b = (const float*)d_in[3];
    const float* w_xp   = (const float*)d_in[4];
    const float* A_log  = (const float*)d_in[5];
    const float* Dv     = (const float*)d_in[6];
    const float* w_out  = (const float*)d_in[7];

    char* base = (char*)d_ws;
    f16* xzh = (f16*)base;                          // 134217728 B
    char* r1 = base + 134217728;                    // 67108864 B shared region
    f16* xh  = (f16*)r1;                            // 33554432 B   (phase A)
    f16* wih = (f16*)(r1 + 33554432);               // 8388608 B    (phase A)
    f16* xch = (f16*)r1;                            // 67108864 B   (phase B)
    f16* woh = (f16*)r1;                            // 4194304 B    (phase C)
    char* p = base + 201326592;
    float* xdbl = (float*)p;  p += 2162688;         // 16384x33
    float* dlt  = (float*)p;  p += 65536;           // 16384
    float* SP   = (float*)p;  p += 3145728;         // 16384x48
    float* G    = (float*)p;  p += 4096;            // 64x16
    float* F    = (float*)p;  p += 8388608;         // 64x2048x16
    float* H0   = (float*)p;  p += 8388608;         // 64x2048x16  (end 223481856)

    // dtype conversions for GEMM1
    cvt_f16_k<<<16384, 256, 0, stream>>>(x, xh, 4194304);
    cvt_f16_k<<<4096, 256, 0, stream>>>(w_in, wih, 1048576);

    // xz = x @ in_proj_w^T   (M=16384, N=4096, K=1024)
    gemm_tn<f16><<<4096, 256, 0, stream>>>(xh, wih, xzh, 16384, 4096, 1024, 1024, 4096);

    // depthwise conv + SiLU -> x_conv   (xh/wih dead; xch overlays them)
    conv_silu_k<<<16384, 256, 0, stream>>>(xzh, conv_w, conv_b, xch);

    // x_dbl = x_conv @ x_proj_w^T  (N=33)
    xdbl_k<<<256, 256, 0, stream>>>(xch, w_xp, xdbl);

    // per-(b,t) scan coefficients
    sp_build_k<<<64, 256, 0, stream>>>(xdbl, A_log, SP, dlt);
    g_build_k<<<64, 256, 0, stream>>>(dlt, A_log, G);

    // chunked selective scan (T=256, 16 chunks)
    scan1_k<<<512, 256, 0, stream>>>(xch, SP, F);
    combine_k<<<32, 256, 0, stream>>>(F, G, H0);
    scan2_k<<<512, 256, 0, stream>>>(xch, xzh, SP, H0, Dv, xzh);

    // convert out_proj_w late (xch dead; woh overlays region1)
    cvt_f16_k<<<2048, 256, 0, stream>>>(w_out, woh, 524288);

    // out = y @ out_proj_w^T  (M=16384, N=1024, K=2048, lda=4096, fp32 out)
    gemm_tn<float><<<1024, 256, 0, stream>>>(xzh, woh, (float*)d_out,
                                             16384, 1024, 2048, 4096, 1024);
}

// Round 3
// 649.970 us; speedup vs baseline: 1.4036x; 1.4036x over previous
//
#include <hip/hip_runtime.h>
#include <hip/hip_fp16.h>

typedef _Float16 f16;
typedef _Float16 half8 __attribute__((ext_vector_type(8)));
typedef _Float16 half4v __attribute__((ext_vector_type(4)));
typedef float f32x4 __attribute__((ext_vector_type(4)));

#define AS1(p) ((const __attribute__((address_space(1))) void*)(p))
#define AS3(p) ((__attribute__((address_space(3))) void*)(p))

__device__ __forceinline__ void gload_lds16(const void* g, void* l) {
    __builtin_amdgcn_global_load_lds(AS1(g), AS3(l), 16, 0, 0);
}

// ---------------------------------------------------------------------------
// f32 -> f16 conversion (vectorized x4)
// ---------------------------------------------------------------------------
__global__ __launch_bounds__(256) void cvt_f16_k(const float* __restrict__ in,
                                                 f16* __restrict__ out, int n4) {
    int i = blockIdx.x * 256 + threadIdx.x;
    if (i < n4) {
        float4 v = ((const float4*)in)[i];
        half4v o;
        o[0] = (f16)v.x; o[1] = (f16)v.y; o[2] = (f16)v.z; o[3] = (f16)v.w;
        ((half4v*)out)[i] = o;
    }
}

// ---------------------------------------------------------------------------
// x_proj_w (33x2048 f32) -> zero-padded 48x2048 f16
// ---------------------------------------------------------------------------
__global__ __launch_bounds__(256)
void wxp_cvt_k(const float* __restrict__ W, f16* __restrict__ Wh) {
    int idx = blockIdx.x * 256 + threadIdx.x;   // 0..98303
    int e = idx >> 11;
    int k = idx & 2047;
    Wh[idx] = (e < 33) ? (f16)W[e * 2048 + k] : (f16)0.f;
}

// ---------------------------------------------------------------------------
// GEMM: C[M,N] = A[M,K(lda)] * B[N,K]^T   (m97 structure, f16 MFMA 16x16x32)
// 128x128 tile, BK=64, 4 waves, 2x2 wave grid, 4x4 frags/wave
// ---------------------------------------------------------------------------
template <typename OutT>
__global__ __launch_bounds__(256, 2)
void gemm_tn(const f16* __restrict__ A, const f16* __restrict__ B,
             OutT* __restrict__ C, int M, int N, int K, int lda, int ldc) {
    __shared__ f16 As[128 * 64];
    __shared__ f16 Bs[128 * 64];

    int nTn = N >> 7;
    unsigned bid = blockIdx.x;
    unsigned cpx = gridDim.x >> 3;           // grid divisible by 8 (XCD swizzle)
    bid = (bid & 7u) * cpx + (bid >> 3);
    int bm = (int)(bid / nTn) * 128;
    int bn = (int)(bid % nTn) * 128;

    int tid = threadIdx.x;
    int wave = tid >> 6;
    int lane = tid & 63;
    int srow = lane >> 3;          // 0..7 (row within 8-row slot)
    int scol = (lane & 7) * 8;     // half offset within row

    int lr = lane & 15;
    int lkh = (lane >> 4) * 8;     // k offset (halfs) within 32

    f32x4 acc[4][4];
#pragma unroll
    for (int i = 0; i < 4; ++i)
#pragma unroll
        for (int j = 0; j < 4; ++j) acc[i][j] = (f32x4){0.f, 0.f, 0.f, 0.f};

    int wm = (wave >> 1) * 64;
    int wn = (wave & 1) * 64;

    for (int k0 = 0; k0 < K; k0 += 64) {
        __syncthreads();  // previous tile fully consumed
#pragma unroll
        for (int i = 0; i < 4; ++i) {
            int slot = wave * 4 + i;
            int row = slot * 8 + srow;
            gload_lds16(A + (size_t)(bm + row) * lda + (k0 + scol), As + slot * 512);
            gload_lds16(B + (size_t)(bn + row) * (size_t)K + (k0 + scol), Bs + slot * 512);
        }
        asm volatile("s_waitcnt vmcnt(0)" ::: "memory");
        __syncthreads();
#pragma unroll
        for (int kk = 0; kk < 2; ++kk) {
            half8 a[4], b[4];
#pragma unroll
            for (int mi = 0; mi < 4; ++mi)
                a[mi] = *(const half8*)(As + (wm + mi * 16 + lr) * 64 + kk * 32 + lkh);
#pragma unroll
            for (int nj = 0; nj < 4; ++nj)
                b[nj] = *(const half8*)(Bs + (wn + nj * 16 + lr) * 64 + kk * 32 + lkh);
#pragma unroll
            for (int mi = 0; mi < 4; ++mi)
#pragma unroll
                for (int nj = 0; nj < 4; ++nj)
                    acc[mi][nj] = __builtin_amdgcn_mfma_f32_16x16x32_f16(
                        a[mi], b[nj], acc[mi][nj], 0, 0, 0);
        }
    }

    int orow0 = bm + wm + (lane >> 4) * 4;
    int ocol0 = bn + wn + lr;
#pragma unroll
    for (int mi = 0; mi < 4; ++mi)
#pragma unroll
        for (int nj = 0; nj < 4; ++nj)
#pragma unroll
            for (int r = 0; r < 4; ++r)
                C[(size_t)(orow0 + mi * 16 + r) * ldc + (ocol0 + nj * 16)] =
                    (OutT)acc[mi][nj][r];
}

// ---------------------------------------------------------------------------
// x_dbl = x_conv @ Wh^T  (M=16384, N=48 padded from 33, K=2048) via MFMA.
// BM=64, BK=64, 4 waves; wave w owns rows [w*16, w*16+16), 3 N-frags.
// Stores only cols < 33 as fp32.
// ---------------------------------------------------------------------------
__global__ __launch_bounds__(256, 2)
void xdbl_mfma_k(const f16* __restrict__ xc, const f16* __restrict__ Wh,
                 float* __restrict__ xdbl) {
    __shared__ f16 As[64 * 64];   // 8 KB
    __shared__ f16 Bs[48 * 64];   // 6 KB
    int bm = blockIdx.x * 64;
    int tid = threadIdx.x;
    int wave = tid >> 6;
    int lane = tid & 63;
    int srow = lane >> 3;
    int scol = (lane & 7) * 8;
    int lr = lane & 15;
    int lkh = (lane >> 4) * 8;

    f32x4 acc[3];
#pragma unroll
    for (int j = 0; j < 3; ++j) acc[j] = (f32x4){0.f, 0.f, 0.f, 0.f};

    for (int k0 = 0; k0 < 2048; k0 += 64) {
        __syncthreads();
#pragma unroll
        for (int i = 0; i < 2; ++i) {
            int slot = wave * 2 + i;          // 0..7 -> A rows slot*8+srow
            gload_lds16(xc + (size_t)(bm + slot * 8 + srow) * 2048 + (k0 + scol),
                        As + slot * 512);
        }
        if (wave < 3) {
#pragma unroll
            for (int i = 0; i < 2; ++i) {
                int slot = wave * 2 + i;      // 0..5 -> B rows slot*8+srow
                gload_lds16(Wh + (size_t)(slot * 8 + srow) * 2048 + (k0 + scol),
                            Bs + slot * 512);
            }
        }
        asm volatile("s_waitcnt vmcnt(0)" ::: "memory");
        __syncthreads();
#pragma unroll
        for (int kk = 0; kk < 2; ++kk) {
            half8 a = *(const half8*)(As + (wave * 16 + lr) * 64 + kk * 32 + lkh);
#pragma unroll
            for (int nj = 0; nj < 3; ++nj) {
                half8 b = *(const half8*)(Bs + (nj * 16 + lr) * 64 + kk * 32 + lkh);
                acc[nj] = __builtin_amdgcn_mfma_f32_16x16x32_f16(a, b, acc[nj], 0, 0, 0);
            }
        }
    }

    int orow0 = bm + wave * 16 + (lane >> 4) * 4;
#pragma unroll
    for (int nj = 0; nj < 3; ++nj) {
        int col = nj * 16 + lr;
        if (col < 33) {
#pragma unroll
            for (int r = 0; r < 4; ++r)
                xdbl[(size_t)(orow0 + r) * 33 + col] = acc[nj][r];
        }
    }
}

// ---------------------------------------------------------------------------
// Depthwise causal conv (k=4) + bias + SiLU.  One block per row m, 8 d/thread.
// ---------------------------------------------------------------------------
__global__ __launch_bounds__(256)
void conv_silu_k(const f16* __restrict__ xz, const float* __restrict__ cw,
                 const float* __restrict__ cb, f16* __restrict__ xc) {
    int m = blockIdx.x;          // 0..16383
    int d0 = threadIdx.x << 3;   // 0..2040
    int l = m & 4095;

    const float4* cw4 = (const float4*)cw;
    float4 w[8];
    float acc[8];
#pragma unroll
    for (int e = 0; e < 8; ++e) {
        w[e] = cw4[d0 + e];
        acc[e] = cb[d0 + e];
    }
#pragma unroll
    for (int j = 0; j < 4; ++j) {
        if (l - 3 + j >= 0) {
            half8 xv = *(const half8*)(xz + (size_t)(m - 3 + j) * 4096 + d0);
#pragma unroll
            for (int e = 0; e < 8; ++e) {
                float wj = (j == 0) ? w[e].x : (j == 1) ? w[e].y : (j == 2) ? w[e].z : w[e].w;
                acc[e] = fmaf((float)xv[e], wj, acc[e]);
            }
        }
    }
    half8 out = {};
#pragma unroll
    for (int e = 0; e < 8; ++e) {
        float v = acc[e];
        out[e] = (f16)(v / (1.f + expf(-v)));
    }
    *(half8*)(xc + (size_t)m * 2048 + d0) = out;
}

// ---------------------------------------------------------------------------
// SP[m][48] = { dA[16]=exp(A_n*delta), dB[16]=delta*B, C[16] }, delta out
// ---------------------------------------------------------------------------
__global__ __launch_bounds__(256)
void sp_build_k(const float* __restrict__ xdbl, const float* __restrict__ A_log,
                float* __restrict__ SP, float* __restrict__ dlt) {
    int m = blockIdx.x * 256 + threadIdx.x;
    const float* row = xdbl + (size_t)m * 33;
    float v0 = row[0];
    float d = (v0 > 15.f) ? v0 : logf(1.f + expf(v0));  // softplus
    dlt[m] = d;
    float* sp = SP + (size_t)m * 48;
#pragma unroll
    for (int n = 0; n < 16; ++n) {
        float An = -expf(A_log[n]);
        sp[n] = expf(An * d);
        sp[16 + n] = d * row[1 + n];
        sp[32 + n] = row[17 + n];
    }
}

// ---------------------------------------------------------------------------
// G[bc][n] = exp(A_n * sum_{t in chunk} delta)   (chunk transition scalars)
// ---------------------------------------------------------------------------
__global__ __launch_bounds__(256)
void g_build_k(const float* __restrict__ dlt, const float* __restrict__ A_log,
               float* __restrict__ G) {
    __shared__ float red[256];
    int bc = blockIdx.x, t = threadIdx.x;
    red[t] = dlt[bc * 256 + t];
    __syncthreads();
#pragma unroll
    for (int s = 128; s > 0; s >>= 1) {
        if (t < s) red[t] += red[t + s];
        __syncthreads();
    }
    if (t < 16) G[bc * 16 + t] = expf(-expf(A_log[t]) * red[0]);
}

// ---------------------------------------------------------------------------
// Scan pass 1: per (b,c,d) local scan with h0=0; write final state F.
// blk = (bc*8 + dg); chunk T=256; SP chunk staged in LDS.
// ---------------------------------------------------------------------------
__global__ __launch_bounds__(256)
void scan1_k(const f16* __restrict__ xc, const float* __restrict__ SP,
             float* __restrict__ F) {
    __shared__ float sp[256 * 48];
    int blk = blockIdx.x;
    int dg = blk & 7;
    int bc = blk >> 3;
    int tid = threadIdx.x;
    int wave = tid >> 6;
    int d = dg * 256 + tid;
    int mbase = bc * 256;

    const char* spb = (const char*)(SP + (size_t)mbase * 48);
#pragma unroll
    for (int i = 0; i < 12; ++i)
        gload_lds16(spb + (size_t)(i * 256 + tid) * 16,
                    (char*)sp + (size_t)(i * 256 + wave * 64) * 16);
    asm volatile("s_waitcnt vmcnt(0)" ::: "memory");
    __syncthreads();

    float h[16];
#pragma unroll
    for (int n = 0; n < 16; ++n) h[n] = 0.f;

#pragma unroll 2
    for (int tt = 0; tt < 256; ++tt) {
        const float* r = sp + tt * 48;
        float x = (float)xc[(size_t)(mbase + tt) * 2048 + d];
#pragma unroll
        for (int n = 0; n < 16; ++n) h[n] = fmaf(h[n], r[n], x * r[16 + n]);
    }
    size_t fb = ((size_t)bc * 2048 + d) * 16;
#pragma unroll
    for (int n = 0; n < 16; ++n) F[fb + n] = h[n];
}

// ---------------------------------------------------------------------------
// Combine: sequential over 16 chunks per (b,d) chain: H0[c]=state before c.
// ---------------------------------------------------------------------------
__global__ __launch_bounds__(256)
void combine_k(const float* __restrict__ F, const float* __restrict__ G,
               float* __restrict__ H0) {
    int gid = blockIdx.x * 256 + threadIdx.x;  // 8192 chains
    int b = gid >> 11;
    int d = gid & 2047;
    float h[16];
#pragma unroll
    for (int n = 0; n < 16; ++n) h[n] = 0.f;
    for (int c = 0; c < 16; ++c) {
        int bc = b * 16 + c;
        size_t base = ((size_t)bc * 2048 + d) * 16;
#pragma unroll
        for (int n = 0; n < 16; ++n) H0[base + n] = h[n];
#pragma unroll
        for (int n = 0; n < 16; ++n) h[n] = fmaf(G[bc * 16 + n], h[n], F[base + n]);
    }
}

// ---------------------------------------------------------------------------
// Scan pass 2: replay with correct h0, emit y = (scan_y + x*D) * silu(z).
// y written into dead x_inner columns of xz buffer (cols 0..2047).
// ---------------------------------------------------------------------------
__global__ __launch_bounds__(256)
void scan2_k(const f16* __restrict__ xc, const f16* xz, const float* __restrict__ SP,
             const float* __restrict__ H0, const float* __restrict__ Dv,
             f16* yout) {
    __shared__ float sp[256 * 48];
    int blk = blockIdx.x;
    int dg = blk & 7;
    int bc = blk >> 3;
    int tid = threadIdx.x;
    int wave = tid >> 6;
    int d = dg * 256 + tid;
    int mbase = bc * 256;

    const char* spb = (const char*)(SP + (size_t)mbase * 48);
#pragma unroll
    for (int i = 0; i < 12; ++i)
        gload_lds16(spb + (size_t)(i * 256 + tid) * 16,
                    (char*)sp + (size_t)(i * 256 + wave * 64) * 16);
    asm volatile("s_waitcnt vmcnt(0)" ::: "memory");
    __syncthreads();

    size_t fb = ((size_t)bc * 2048 + d) * 16;
    float h[16];
#pragma unroll
    for (int n = 0; n < 16; ++n) h[n] = H0[fb + n];
    float Dd = Dv[d];

#pragma unroll 2
    for (int tt = 0; tt < 256; ++tt) {
        const float* r = sp + tt * 48;
        size_t mrow = (size_t)(mbase + tt);
        float x = (float)xc[mrow * 2048 + d];
        float z = (float)xz[mrow * 4096 + 2048 + d];
        float y0 = 0.f, y1 = 0.f, y2 = 0.f, y3 = 0.f;
#pragma unroll
        for (int n = 0; n < 16; n += 4) {
            h[n]     = fmaf(h[n],     r[n],     x * r[16 + n]);
            h[n + 1] = fmaf(h[n + 1], r[n + 1], x * r[17 + n]);
            h[n + 2] = fmaf(h[n + 2], r[n + 2], x * r[18 + n]);
            h[n + 3] = fmaf(h[n + 3], r[n + 3], x * r[19 + n]);
            y0 = fmaf(h[n],     r[32 + n], y0);
            y1 = fmaf(h[n + 1], r[33 + n], y1);
            y2 = fmaf(h[n + 2], r[34 + n], y2);
            y3 = fmaf(h[n + 3], r[35 + n], y3);
        }
        float y = (y0 + y1) + (y2 + y3);
        float yf = fmaf(x, Dd, y);
        float sz = z / (1.f + expf(-z));
        yout[mrow * 4096 + d] = (f16)(yf * sz);
    }
}

// ---------------------------------------------------------------------------
// Workspace layout (aliased by lifetime; peak ~223.7 MB < 256 MiB):
//   [0,   134217728)  xzh  : f16 16384x4096 (x_inner|z; x_inner cols become y)
//   [134217728, +67108864) region1:
//        phase A (cvt+GEMM1):  xh f16 16384x1024 @ +0, wih f16 4096x1024 @ +33554432
//        phase B (conv..scan2): xch f16 16384x2048 @ +0
//        phase C (final GEMM):  woh f16 1024x2048 @ +0  (converted after scan2)
//   [201326592, ...)  xdbl(2162688) dlt(65536) SP(3145728) G(4096) F(8388608)
//                     H0(8388608) Wh(196608)   end = 223678464
// ---------------------------------------------------------------------------
extern "C" void kernel_launch(void* const* d_in, const int* in_sizes, int n_in,
                              void* d_out, int out_size, void* d_ws, size_t ws_size,
                              hipStream_t stream) {
    const float* x      = (const float*)d_in[0];
    const float* w_in   = (const float*)d_in[1];
    const float* conv_w = (const float*)d_in[2];
    const float* conv_b = (const float*)d_in[3];
    const float* w_xp   = (const float*)d_in[4];
    const float* A_log  = (const float*)d_in[5];
    const float* Dv     = (const float*)d_in[6];
    const float* w_out  = (const float*)d_in[7];

    char* base = (char*)d_ws;
    f16* xzh = (f16*)base;                          // 134217728 B
    char* r1 = base + 134217728;                    // 67108864 B shared region
    f16* xh  = (f16*)r1;                            // 33554432 B   (phase A)
    f16* wih = (f16*)(r1 + 33554432);               // 8388608 B    (phase A)
    f16* xch = (f16*)r1;                            // 67108864 B   (phase B)
    f16* woh = (f16*)r1;                            // 4194304 B    (phase C)
    char* p = base + 201326592;
    float* xdbl = (float*)p;  p += 2162688;         // 16384x33
    float* dlt  = (float*)p;  p += 65536;           // 16384
    float* SP   = (float*)p;  p += 3145728;         // 16384x48
    float* G    = (float*)p;  p += 4096;            // 64x16
    float* F    = (float*)p;  p += 8388608;         // 64x2048x16
    float* H0   = (float*)p;  p += 8388608;         // 64x2048x16
    f16*   Wh   = (f16*)p;    p += 196608;          // 48x2048 f16 padded x_proj_w

    // dtype conversions for GEMM1 + padded x_proj_w
    cvt_f16_k<<<16384, 256, 0, stream>>>(x, xh, 4194304);
    cvt_f16_k<<<4096, 256, 0, stream>>>(w_in, wih, 1048576);
    wxp_cvt_k<<<384, 256, 0, stream>>>(w_xp, Wh);

    // xz = x @ in_proj_w^T   (M=16384, N=4096, K=1024)
    gemm_tn<f16><<<4096, 256, 0, stream>>>(xh, wih, xzh, 16384, 4096, 1024, 1024, 4096);

    // depthwise conv + SiLU -> x_conv   (xh/wih dead; xch overlays them)
    conv_silu_k<<<16384, 256, 0, stream>>>(xzh, conv_w, conv_b, xch);

    // x_dbl = x_conv @ x_proj_w^T  (N=33 padded to 48) via MFMA
    xdbl_mfma_k<<<256, 256, 0, stream>>>(xch, Wh, xdbl);

    // per-(b,t) scan coefficients
    sp_build_k<<<64, 256, 0, stream>>>(xdbl, A_log, SP, dlt);
    g_build_k<<<64, 256, 0, stream>>>(dlt, A_log, G);

    // chunked selective scan (T=256, 16 chunks)
    scan1_k<<<512, 256, 0, stream>>>(xch, SP, F);
    combine_k<<<32, 256, 0, stream>>>(F, G, H0);
    scan2_k<<<512, 256, 0, stream>>>(xch, xzh, SP, H0, Dv, xzh);

    // convert out_proj_w late (xch dead; woh overlays region1)
    cvt_f16_k<<<2048, 256, 0, stream>>>(w_out, woh, 524288);

    // out = y @ out_proj_w^T  (M=16384, N=1024, K=2048, lda=4096, fp32 out)
    gemm_tn<float><<<1024, 256, 0, stream>>>(xzh, woh, (float*)d_out,
                                             16384, 1024, 2048, 4096, 1024);
}

// Round 4
// 591.118 us; speedup vs baseline: 1.5434x; 1.0996x over previous
//
#include <hip/hip_runtime.h>
#include <hip/hip_fp16.h>

typedef _Float16 f16;
typedef _Float16 half8 __attribute__((ext_vector_type(8)));
typedef _Float16 half4v __attribute__((ext_vector_type(4)));
typedef float f32x4 __attribute__((ext_vector_type(4)));

#define AS1(p) ((const __attribute__((address_space(1))) void*)(p))
#define AS3(p) ((__attribute__((address_space(3))) void*)(p))

__device__ __forceinline__ void gload_lds16(const void* g, void* l) {
    __builtin_amdgcn_global_load_lds(AS1(g), AS3(l), 16, 0, 0);
}

// ---------------------------------------------------------------------------
// f32 -> f16 conversion (vectorized x4)
// ---------------------------------------------------------------------------
__global__ __launch_bounds__(256) void cvt_f16_k(const float* __restrict__ in,
                                                 f16* __restrict__ out, int n4) {
    int i = blockIdx.x * 256 + threadIdx.x;
    if (i < n4) {
        float4 v = ((const float4*)in)[i];
        half4v o;
        o[0] = (f16)v.x; o[1] = (f16)v.y; o[2] = (f16)v.z; o[3] = (f16)v.w;
        ((half4v*)out)[i] = o;
    }
}

// ---------------------------------------------------------------------------
// x_proj_w (33x2048 f32) -> zero-padded 48x2048 f16
// ---------------------------------------------------------------------------
__global__ __launch_bounds__(256)
void wxp_cvt_k(const float* __restrict__ W, f16* __restrict__ Wh) {
    int idx = blockIdx.x * 256 + threadIdx.x;   // 0..98303
    int e = idx >> 11;
    int k = idx & 2047;
    Wh[idx] = (e < 33) ? (f16)W[e * 2048 + k] : (f16)0.f;
}

// ===========================================================================
// 256x256 8-phase GEMM (T2+T3+T4+T5 port of the m201 template, f16 MFMA).
// C[M,N] = A[M,K(lda)] * B[N,K]^T.  BK=64, 8 waves (2M x 4N), 512 threads.
// LDS: 2 dbuf x {A,B} x {kh0,kh1} quarters of 16KB = 128 KiB.
// Quarter layout: [256 rows][32 halfs], 64B rows, chunk swizzle
//   chunk' = chunk ^ ((row>>1)&3)   (involution; applied on write-source and
//   read-offset; gives 2-way (free) bank access for the 16-lane row groups).
// Quarter free/overwrite schedule per K-tile (phases = (kh,mh)):
//   B-kh0 last read ph1 -> overwrite issued ph2(+4)
//   A-kh0 last read ph2 -> issued ph3(+4)
//   B-kh1 last read ph3 -> issued ph4(+4)
//   A-kh1 last read ph4 -> issued ph5(+4)
// vmcnt(6) at ph4/ph8 = 3 quarters (2 loads each) in flight; the 8 older
// loads (the next K-tile's 4 quarters) are complete.  Last iter: vmcnt(0).
// ===========================================================================
__device__ __forceinline__ void stage_q(const f16* __restrict__ g, int ld,
                                        int row0, int gk, f16* q,
                                        int tid, int wave) {
#pragma unroll
    for (int rd = 0; rd < 2; ++rd) {
        int t = rd * 512 + tid;
        int r = t >> 2;                       // row 0..255
        int cu = (t & 3) ^ ((r >> 1) & 3);    // unswizzled chunk for this slot
        gload_lds16(g + (size_t)(row0 + r) * ld + gk + cu * 8,
                    q + rd * 4096 + wave * 512);   // wave-uniform linear dest
    }
}

#define PH(Q, KH, MH, LOADB, STAGE, WAITC)                                    \
  {                                                                           \
    half8 afr[4];                                                             \
    {                                                                         \
      const f16* aq = &lds[Q][0][KH][0];                                      \
      int ra = wm * 128 + (MH) * 64 + lr;                                     \
      afr[0] = *(const half8*)(aq + (ra +  0) * 32 + cofs);                   \
      afr[1] = *(const half8*)(aq + (ra + 16) * 32 + cofs);                   \
      afr[2] = *(const half8*)(aq + (ra + 32) * 32 + cofs);                   \
      afr[3] = *(const half8*)(aq + (ra + 48) * 32 + cofs);                   \
    }                                                                         \
    if (LOADB) {                                                              \
      const f16* bq = &lds[Q][1][KH][0];                                      \
      int rb = wn * 64 + lr;                                                  \
      bfr[0] = *(const half8*)(bq + (rb +  0) * 32 + cofs);                   \
      bfr[1] = *(const half8*)(bq + (rb + 16) * 32 + cofs);                   \
      bfr[2] = *(const half8*)(bq + (rb + 32) * 32 + cofs);                   \
      bfr[3] = *(const half8*)(bq + (rb + 48) * 32 + cofs);                   \
    }                                                                         \
    STAGE;                                                                    \
    __builtin_amdgcn_s_barrier();                                             \
    asm volatile("s_waitcnt lgkmcnt(0)" ::: "memory");                        \
    __builtin_amdgcn_sched_barrier(0);                                        \
    __builtin_amdgcn_s_setprio(1);                                            \
    _Pragma("unroll")                                                         \
    for (int f_ = 0; f_ < 4; ++f_)                                            \
      _Pragma("unroll")                                                       \
      for (int j_ = 0; j_ < 4; ++j_)                                          \
        acc[(MH) * 4 + f_][j_] = __builtin_amdgcn_mfma_f32_16x16x32_f16(      \
            afr[f_], bfr[j_], acc[(MH) * 4 + f_][j_], 0, 0, 0);               \
    __builtin_amdgcn_s_setprio(0);                                            \
    __builtin_amdgcn_sched_barrier(0);                                        \
    WAITC;                                                                    \
    __builtin_amdgcn_s_barrier();                                             \
  }

template <typename OutT>
__global__ __launch_bounds__(512, 2)
void gemm8p(const f16* __restrict__ A, const f16* __restrict__ B,
            OutT* __restrict__ C, int N, int K, int lda, int ldc) {
    __shared__ f16 lds[2][2][2][8192];   // [buf][A/B][kh][quarter] = 128 KiB

    int nTn = N >> 8;
    unsigned bid = blockIdx.x;
    unsigned cpx = gridDim.x >> 3;        // grid divisible by 8 (XCD swizzle)
    bid = (bid & 7u) * cpx + (bid >> 3);
    int bm = (int)(bid / nTn) * 256;
    int bn = (int)(bid % nTn) * 256;

    int tid = threadIdx.x;
    int wave = tid >> 6;
    int lane = tid & 63;
    int wm = wave >> 2;                   // 0..1
    int wn = wave & 3;                    // 0..3
    int lr = lane & 15;
    int cg = lane >> 4;                   // chunk group 0..3
    int cofs = ((cg ^ ((lr >> 1) & 3)) << 3);   // swizzled chunk offset (halfs)

    f32x4 acc[8][4];
#pragma unroll
    for (int i = 0; i < 8; ++i)
#pragma unroll
        for (int j = 0; j < 4; ++j) acc[i][j] = (f32x4){0.f, 0.f, 0.f, 0.f};
    half8 bfr[4];

    // prologue: kt0 fully (8 loads), kt1 B0/A0/B1 (6 loads); kt1 A1 at ph1
    stage_q(B, K,   bn, 0,  &lds[0][1][0][0], tid, wave);
    stage_q(A, lda, bm, 0,  &lds[0][0][0][0], tid, wave);
    stage_q(B, K,   bn, 32, &lds[0][1][1][0], tid, wave);
    stage_q(A, lda, bm, 32, &lds[0][0][1][0], tid, wave);
    stage_q(B, K,   bn, 64, &lds[1][1][0][0], tid, wave);
    stage_q(A, lda, bm, 64, &lds[1][0][0][0], tid, wave);
    stage_q(B, K,   bn, 96, &lds[1][1][1][0], tid, wave);
    asm volatile("s_waitcnt vmcnt(6)" ::: "memory");
    __builtin_amdgcn_s_barrier();

    int NI = K >> 7;                      // 2 K-tiles per iteration
    for (int it = 0; it < NI; ++it) {
        int gk = it << 7;
        bool last = (it == NI - 1);
        // --- K-tile kt0 = 2it (buf 0) ---
        PH(0, 0, 0, true,
           { stage_q(A, lda, bm, gk + 96, &lds[1][0][1][0], tid, wave); }, {});
        PH(0, 0, 1, false,
           { if (!last) stage_q(B, K, bn, gk + 128, &lds[0][1][0][0], tid, wave); }, {});
        PH(0, 1, 0, true,
           { if (!last) stage_q(A, lda, bm, gk + 128, &lds[0][0][0][0], tid, wave); }, {});
        PH(0, 1, 1, false,
           { if (!last) stage_q(B, K, bn, gk + 160, &lds[0][1][1][0], tid, wave); },
           { if (last) asm volatile("s_waitcnt vmcnt(0)" ::: "memory");
             else      asm volatile("s_waitcnt vmcnt(6)" ::: "memory"); });
        // --- K-tile kt1 = 2it+1 (buf 1) ---
        PH(1, 0, 0, true,
           { if (!last) stage_q(A, lda, bm, gk + 160, &lds[0][0][1][0], tid, wave); }, {});
        PH(1, 0, 1, false,
           { if (!last) stage_q(B, K, bn, gk + 192, &lds[1][1][0][0], tid, wave); }, {});
        PH(1, 1, 0, true,
           { if (!last) stage_q(A, lda, bm, gk + 192, &lds[1][0][0][0], tid, wave); }, {});
        PH(1, 1, 1, false,
           { if (!last) stage_q(B, K, bn, gk + 224, &lds[1][1][1][0], tid, wave); },
           { if (!last) asm volatile("s_waitcnt vmcnt(6)" ::: "memory"); });
    }

    int orow0 = bm + wm * 128 + (lane >> 4) * 4;
    int ocol0 = bn + wn * 64 + lr;
#pragma unroll
    for (int mf = 0; mf < 8; ++mf)
#pragma unroll
        for (int nj = 0; nj < 4; ++nj)
#pragma unroll
            for (int r = 0; r < 4; ++r)
                C[(size_t)(orow0 + mf * 16 + r) * ldc + (ocol0 + nj * 16)] =
                    (OutT)acc[mf][nj][r];
}

// ---------------------------------------------------------------------------
// x_dbl = x_conv @ Wh^T  (M=16384, N=48 padded from 33, K=2048) via MFMA.
// ---------------------------------------------------------------------------
__global__ __launch_bounds__(256, 2)
void xdbl_mfma_k(const f16* __restrict__ xc, const f16* __restrict__ Wh,
                 float* __restrict__ xdbl) {
    __shared__ f16 As[64 * 64];   // 8 KB
    __shared__ f16 Bs[48 * 64];   // 6 KB
    int bm = blockIdx.x * 64;
    int tid = threadIdx.x;
    int wave = tid >> 6;
    int lane = tid & 63;
    int srow = lane >> 3;
    int scol = (lane & 7) * 8;
    int lr = lane & 15;
    int lkh = (lane >> 4) * 8;

    f32x4 acc[3];
#pragma unroll
    for (int j = 0; j < 3; ++j) acc[j] = (f32x4){0.f, 0.f, 0.f, 0.f};

    for (int k0 = 0; k0 < 2048; k0 += 64) {
        __syncthreads();
#pragma unroll
        for (int i = 0; i < 2; ++i) {
            int slot = wave * 2 + i;
            gload_lds16(xc + (size_t)(bm + slot * 8 + srow) * 2048 + (k0 + scol),
                        As + slot * 512);
        }
        if (wave < 3) {
#pragma unroll
            for (int i = 0; i < 2; ++i) {
                int slot = wave * 2 + i;
                gload_lds16(Wh + (size_t)(slot * 8 + srow) * 2048 + (k0 + scol),
                            Bs + slot * 512);
            }
        }
        asm volatile("s_waitcnt vmcnt(0)" ::: "memory");
        __syncthreads();
#pragma unroll
        for (int kk = 0; kk < 2; ++kk) {
            half8 a = *(const half8*)(As + (wave * 16 + lr) * 64 + kk * 32 + lkh);
#pragma unroll
            for (int nj = 0; nj < 3; ++nj) {
                half8 b = *(const half8*)(Bs + (nj * 16 + lr) * 64 + kk * 32 + lkh);
                acc[nj] = __builtin_amdgcn_mfma_f32_16x16x32_f16(a, b, acc[nj], 0, 0, 0);
            }
        }
    }

    int orow0 = bm + wave * 16 + (lane >> 4) * 4;
#pragma unroll
    for (int nj = 0; nj < 3; ++nj) {
        int col = nj * 16 + lr;
        if (col < 33) {
#pragma unroll
            for (int r = 0; r < 4; ++r)
                xdbl[(size_t)(orow0 + r) * 33 + col] = acc[nj][r];
        }
    }
}

// ---------------------------------------------------------------------------
// Depthwise causal conv (k=4) + bias + SiLU.  One block per row m, 8 d/thread.
// ---------------------------------------------------------------------------
__global__ __launch_bounds__(256)
void conv_silu_k(const f16* __restrict__ xz, const float* __restrict__ cw,
                 const float* __restrict__ cb, f16* __restrict__ xc) {
    int m = blockIdx.x;          // 0..16383
    int d0 = threadIdx.x << 3;   // 0..2040
    int l = m & 4095;

    const float4* cw4 = (const float4*)cw;
    float4 w[8];
    float acc[8];
#pragma unroll
    for (int e = 0; e < 8; ++e) {
        w[e] = cw4[d0 + e];
        acc[e] = cb[d0 + e];
    }
#pragma unroll
    for (int j = 0; j < 4; ++j) {
        if (l - 3 + j >= 0) {
            half8 xv = *(const half8*)(xz + (size_t)(m - 3 + j) * 4096 + d0);
#pragma unroll
            for (int e = 0; e < 8; ++e) {
                float wj = (j == 0) ? w[e].x : (j == 1) ? w[e].y : (j == 2) ? w[e].z : w[e].w;
                acc[e] = fmaf((float)xv[e], wj, acc[e]);
            }
        }
    }
    half8 out = {};
#pragma unroll
    for (int e = 0; e < 8; ++e) {
        float v = acc[e];
        out[e] = (f16)(v / (1.f + expf(-v)));
    }
    *(half8*)(xc + (size_t)m * 2048 + d0) = out;
}

// ---------------------------------------------------------------------------
// SP[m][48] = { dA[16]=exp(A_n*delta), dB[16]=delta*B, C[16] }, delta out
// ---------------------------------------------------------------------------
__global__ __launch_bounds__(256)
void sp_build_k(const float* __restrict__ xdbl, const float* __restrict__ A_log,
                float* __restrict__ SP, float* __restrict__ dlt) {
    int m = blockIdx.x * 256 + threadIdx.x;
    const float* row = xdbl + (size_t)m * 33;
    float v0 = row[0];
    float d = (v0 > 15.f) ? v0 : logf(1.f + expf(v0));  // softplus
    dlt[m] = d;
    float* sp = SP + (size_t)m * 48;
#pragma unroll
    for (int n = 0; n < 16; ++n) {
        float An = -expf(A_log[n]);
        sp[n] = expf(An * d);
        sp[16 + n] = d * row[1 + n];
        sp[32 + n] = row[17 + n];
    }
}

// ---------------------------------------------------------------------------
// G[bc][n] = exp(A_n * sum_{t in chunk} delta)   (chunk transition scalars)
// ---------------------------------------------------------------------------
__global__ __launch_bounds__(256)
void g_build_k(const float* __restrict__ dlt, const float* __restrict__ A_log,
               float* __restrict__ G) {
    __shared__ float red[256];
    int bc = blockIdx.x, t = threadIdx.x;
    red[t] = dlt[bc * 256 + t];
    __syncthreads();
#pragma unroll
    for (int s = 128; s > 0; s >>= 1) {
        if (t < s) red[t] += red[t + s];
        __syncthreads();
    }
    if (t < 16) G[bc * 16 + t] = expf(-expf(A_log[t]) * red[0]);
}

// ---------------------------------------------------------------------------
// Scan pass 1: per (b,c,d) local scan with h0=0; write final state F.
// ---------------------------------------------------------------------------
__global__ __launch_bounds__(256)
void scan1_k(const f16* __restrict__ xc, const float* __restrict__ SP,
             float* __restrict__ F) {
    __shared__ float sp[256 * 48];
    int blk = blockIdx.x;
    int dg = blk & 7;
    int bc = blk >> 3;
    int tid = threadIdx.x;
    int wave = tid >> 6;
    int d = dg * 256 + tid;
    int mbase = bc * 256;

    const char* spb = (const char*)(SP + (size_t)mbase * 48);
#pragma unroll
    for (int i = 0; i < 12; ++i)
        gload_lds16(spb + (size_t)(i * 256 + tid) * 16,
                    (char*)sp + (size_t)(i * 256 + wave * 64) * 16);
    asm volatile("s_waitcnt vmcnt(0)" ::: "memory");
    __syncthreads();

    float h[16];
#pragma unroll
    for (int n = 0; n < 16; ++n) h[n] = 0.f;

#pragma unroll 2
    for (int tt = 0; tt < 256; ++tt) {
        const float* r = sp + tt * 48;
        float x = (float)xc[(size_t)(mbase + tt) * 2048 + d];
#pragma unroll
        for (int n = 0; n < 16; ++n) h[n] = fmaf(h[n], r[n], x * r[16 + n]);
    }
    size_t fb = ((size_t)bc * 2048 + d) * 16;
#pragma unroll
    for (int n = 0; n < 16; ++n) F[fb + n] = h[n];
}

// ---------------------------------------------------------------------------
// Combine: sequential over 16 chunks per (b,d) chain: H0[c]=state before c.
// ---------------------------------------------------------------------------
__global__ __launch_bounds__(256)
void combine_k(const float* __restrict__ F, const float* __restrict__ G,
               float* __restrict__ H0) {
    int gid = blockIdx.x * 256 + threadIdx.x;  // 8192 chains
    int b = gid >> 11;
    int d = gid & 2047;
    float h[16];
#pragma unroll
    for (int n = 0; n < 16; ++n) h[n] = 0.f;
    for (int c = 0; c < 16; ++c) {
        int bc = b * 16 + c;
        size_t base = ((size_t)bc * 2048 + d) * 16;
#pragma unroll
        for (int n = 0; n < 16; ++n) H0[base + n] = h[n];
#pragma unroll
        for (int n = 0; n < 16; ++n) h[n] = fmaf(G[bc * 16 + n], h[n], F[base + n]);
    }
}

// ---------------------------------------------------------------------------
// Scan pass 2: replay with correct h0, emit y = (scan_y + x*D) * silu(z).
// ---------------------------------------------------------------------------
__global__ __launch_bounds__(256)
void scan2_k(const f16* __restrict__ xc, const f16* xz, const float* __restrict__ SP,
             const float* __restrict__ H0, const float* __restrict__ Dv,
             f16* yout) {
    __shared__ float sp[256 * 48];
    int blk = blockIdx.x;
    int dg = blk & 7;
    int bc = blk >> 3;
    int tid = threadIdx.x;
    int wave = tid >> 6;
    int d = dg * 256 + tid;
    int mbase = bc * 256;

    const char* spb = (const char*)(SP + (size_t)mbase * 48);
#pragma unroll
    for (int i = 0; i < 12; ++i)
        gload_lds16(spb + (size_t)(i * 256 + tid) * 16,
                    (char*)sp + (size_t)(i * 256 + wave * 64) * 16);
    asm volatile("s_waitcnt vmcnt(0)" ::: "memory");
    __syncthreads();

    size_t fb = ((size_t)bc * 2048 + d) * 16;
    float h[16];
#pragma unroll
    for (int n = 0; n < 16; ++n) h[n] = H0[fb + n];
    float Dd = Dv[d];

#pragma unroll 2
    for (int tt = 0; tt < 256; ++tt) {
        const float* r = sp + tt * 48;
        size_t mrow = (size_t)(mbase + tt);
        float x = (float)xc[mrow * 2048 + d];
        float z = (float)xz[mrow * 4096 + 2048 + d];
        float y0 = 0.f, y1 = 0.f, y2 = 0.f, y3 = 0.f;
#pragma unroll
        for (int n = 0; n < 16; n += 4) {
            h[n]     = fmaf(h[n],     r[n],     x * r[16 + n]);
            h[n + 1] = fmaf(h[n + 1], r[n + 1], x * r[17 + n]);
            h[n + 2] = fmaf(h[n + 2], r[n + 2], x * r[18 + n]);
            h[n + 3] = fmaf(h[n + 3], r[n + 3], x * r[19 + n]);
            y0 = fmaf(h[n],     r[32 + n], y0);
            y1 = fmaf(h[n + 1], r[33 + n], y1);
            y2 = fmaf(h[n + 2], r[34 + n], y2);
            y3 = fmaf(h[n + 3], r[35 + n], y3);
        }
        float y = (y0 + y1) + (y2 + y3);
        float yf = fmaf(x, Dd, y);
        float sz = z / (1.f + expf(-z));
        yout[mrow * 4096 + d] = (f16)(yf * sz);
    }
}

// ---------------------------------------------------------------------------
// Workspace layout (aliased by lifetime; peak ~223.7 MB < 256 MiB):
//   [0,   134217728)  xzh  : f16 16384x4096 (x_inner|z; x_inner cols become y)
//   [134217728, +67108864) region1:
//        phase A (cvt+GEMM1):  xh f16 16384x1024 @ +0, wih f16 4096x1024 @ +33554432
//        phase B (conv..scan2): xch f16 16384x2048 @ +0
//        phase C (final GEMM):  woh f16 1024x2048 @ +0  (converted after scan2)
//   [201326592, ...)  xdbl(2162688) dlt(65536) SP(3145728) G(4096) F(8388608)
//                     H0(8388608) Wh(196608)   end = 223678464
// ---------------------------------------------------------------------------
extern "C" void kernel_launch(void* const* d_in, const int* in_sizes, int n_in,
                              void* d_out, int out_size, void* d_ws, size_t ws_size,
                              hipStream_t stream) {
    const float* x      = (const float*)d_in[0];
    const float* w_in   = (const float*)d_in[1];
    const float* conv_w = (const float*)d_in[2];
    const float* conv_b = (const float*)d_in[3];
    const float* w_xp   = (const float*)d_in[4];
    const float* A_log  = (const float*)d_in[5];
    const float* Dv     = (const float*)d_in[6];
    const float* w_out  = (const float*)d_in[7];

    char* base = (char*)d_ws;
    f16* xzh = (f16*)base;                          // 134217728 B
    char* r1 = base + 134217728;                    // 67108864 B shared region
    f16* xh  = (f16*)r1;                            // 33554432 B   (phase A)
    f16* wih = (f16*)(r1 + 33554432);               // 8388608 B    (phase A)
    f16* xch = (f16*)r1;                            // 67108864 B   (phase B)
    f16* woh = (f16*)r1;                            // 4194304 B    (phase C)
    char* p = base + 201326592;
    float* xdbl = (float*)p;  p += 2162688;         // 16384x33
    float* dlt  = (float*)p;  p += 65536;           // 16384
    float* SP   = (float*)p;  p += 3145728;         // 16384x48
    float* G    = (float*)p;  p += 4096;            // 64x16
    float* F    = (float*)p;  p += 8388608;         // 64x2048x16
    float* H0   = (float*)p;  p += 8388608;         // 64x2048x16
    f16*   Wh   = (f16*)p;    p += 196608;          // 48x2048 f16 padded x_proj_w

    // dtype conversions for GEMM1 + padded x_proj_w
    cvt_f16_k<<<16384, 256, 0, stream>>>(x, xh, 4194304);
    cvt_f16_k<<<4096, 256, 0, stream>>>(w_in, wih, 1048576);
    wxp_cvt_k<<<384, 256, 0, stream>>>(w_xp, Wh);

    // xz = x @ in_proj_w^T   (M=16384, N=4096, K=1024) — 8-phase 256² template
    gemm8p<f16><<<1024, 512, 0, stream>>>(xh, wih, xzh, 4096, 1024, 1024, 4096);

    // depthwise conv + SiLU -> x_conv   (xh/wih dead; xch overlays them)
    conv_silu_k<<<16384, 256, 0, stream>>>(xzh, conv_w, conv_b, xch);

    // x_dbl = x_conv @ x_proj_w^T  (N=33 padded to 48) via MFMA
    xdbl_mfma_k<<<256, 256, 0, stream>>>(xch, Wh, xdbl);

    // per-(b,t) scan coefficients
    sp_build_k<<<64, 256, 0, stream>>>(xdbl, A_log, SP, dlt);
    g_build_k<<<64, 256, 0, stream>>>(dlt, A_log, G);

    // chunked selective scan (T=256, 16 chunks)
    scan1_k<<<512, 256, 0, stream>>>(xch, SP, F);
    combine_k<<<32, 256, 0, stream>>>(F, G, H0);
    scan2_k<<<512, 256, 0, stream>>>(xch, xzh, SP, H0, Dv, xzh);

    // convert out_proj_w late (xch dead; woh overlays region1)
    cvt_f16_k<<<2048, 256, 0, stream>>>(w_out, woh, 524288);

    // out = y @ out_proj_w^T  (M=16384, N=1024, K=2048, lda=4096, fp32 out)
    gemm8p<float><<<256, 512, 0, stream>>>(xzh, woh, (float*)d_out,
                                           1024, 2048, 4096, 1024);
}

// Round 5
// 483.585 us; speedup vs baseline: 1.8866x; 1.2224x over previous
//
#include <hip/hip_runtime.h>
#include <hip/hip_fp16.h>

typedef _Float16 f16;
typedef _Float16 half8 __attribute__((ext_vector_type(8)));
typedef _Float16 half4v __attribute__((ext_vector_type(4)));
typedef float f32x4 __attribute__((ext_vector_type(4)));

#define AS1(p) ((const __attribute__((address_space(1))) void*)(p))
#define AS3(p) ((__attribute__((address_space(3))) void*)(p))

__device__ __forceinline__ void gload_lds16(const void* g, void* l) {
    __builtin_amdgcn_global_load_lds(AS1(g), AS3(l), 16, 0, 0);
}

// ---------------------------------------------------------------------------
// f32 -> f16 conversion (vectorized x4, grid-stride)
// ---------------------------------------------------------------------------
__global__ __launch_bounds__(256) void cvt_f16_k(const float* __restrict__ in,
                                                 f16* __restrict__ out, int n4) {
    for (int i = blockIdx.x * 256 + threadIdx.x; i < n4; i += gridDim.x * 256) {
        float4 v = ((const float4*)in)[i];
        half4v o;
        o[0] = (f16)v.x; o[1] = (f16)v.y; o[2] = (f16)v.z; o[3] = (f16)v.w;
        ((half4v*)out)[i] = o;
    }
}

// ---------------------------------------------------------------------------
// x_proj_w (33x2048 f32) -> zero-padded 48x2048 f16
// ---------------------------------------------------------------------------
__global__ __launch_bounds__(256)
void wxp_cvt_k(const float* __restrict__ W, f16* __restrict__ Wh) {
    int idx = blockIdx.x * 256 + threadIdx.x;   // 0..98303
    int e = idx >> 11;
    int k = idx & 2047;
    Wh[idx] = (e < 33) ? (f16)W[e * 2048 + k] : (f16)0.f;
}

// ===========================================================================
// 256x256 8-phase GEMM (T2+T3+T4+T5 port of the m201 template, f16 MFMA).
// See round-4 comments; unchanged this round.
// ===========================================================================
__device__ __forceinline__ void stage_q(const f16* __restrict__ g, int ld,
                                        int row0, int gk, f16* q,
                                        int tid, int wave) {
#pragma unroll
    for (int rd = 0; rd < 2; ++rd) {
        int t = rd * 512 + tid;
        int r = t >> 2;                       // row 0..255
        int cu = (t & 3) ^ ((r >> 1) & 3);    // unswizzled chunk for this slot
        gload_lds16(g + (size_t)(row0 + r) * ld + gk + cu * 8,
                    q + rd * 4096 + wave * 512);   // wave-uniform linear dest
    }
}

#define PH(Q, KH, MH, LOADB, STAGE, WAITC)                                    \
  {                                                                           \
    half8 afr[4];                                                             \
    {                                                                         \
      const f16* aq = &lds[Q][0][KH][0];                                      \
      int ra = wm * 128 + (MH) * 64 + lr;                                     \
      afr[0] = *(const half8*)(aq + (ra +  0) * 32 + cofs);                   \
      afr[1] = *(const half8*)(aq + (ra + 16) * 32 + cofs);                   \
      afr[2] = *(const half8*)(aq + (ra + 32) * 32 + cofs);                   \
      afr[3] = *(const half8*)(aq + (ra + 48) * 32 + cofs);                   \
    }                                                                         \
    if (LOADB) {                                                              \
      const f16* bq = &lds[Q][1][KH][0];                                      \
      int rb = wn * 64 + lr;                                                  \
      bfr[0] = *(const half8*)(bq + (rb +  0) * 32 + cofs);                   \
      bfr[1] = *(const half8*)(bq + (rb + 16) * 32 + cofs);                   \
      bfr[2] = *(const half8*)(bq + (rb + 32) * 32 + cofs);                   \
      bfr[3] = *(const half8*)(bq + (rb + 48) * 32 + cofs);                   \
    }                                                                         \
    STAGE;                                                                    \
    __builtin_amdgcn_s_barrier();                                             \
    asm volatile("s_waitcnt lgkmcnt(0)" ::: "memory");                        \
    __builtin_amdgcn_sched_barrier(0);                                        \
    __builtin_amdgcn_s_setprio(1);                                            \
    _Pragma("unroll")                                                         \
    for (int f_ = 0; f_ < 4; ++f_)                                            \
      _Pragma("unroll")                                                       \
      for (int j_ = 0; j_ < 4; ++j_)                                          \
        acc[(MH) * 4 + f_][j_] = __builtin_amdgcn_mfma_f32_16x16x32_f16(      \
            afr[f_], bfr[j_], acc[(MH) * 4 + f_][j_], 0, 0, 0);               \
    __builtin_amdgcn_s_setprio(0);                                            \
    __builtin_amdgcn_sched_barrier(0);                                        \
    WAITC;                                                                    \
    __builtin_amdgcn_s_barrier();                                             \
  }

template <typename OutT>
__global__ __launch_bounds__(512, 2)
void gemm8p(const f16* __restrict__ A, const f16* __restrict__ B,
            OutT* __restrict__ C, int N, int K, int lda, int ldc) {
    __shared__ f16 lds[2][2][2][8192];   // [buf][A/B][kh][quarter] = 128 KiB

    int nTn = N >> 8;
    unsigned bid = blockIdx.x;
    unsigned cpx = gridDim.x >> 3;        // grid divisible by 8 (XCD swizzle)
    bid = (bid & 7u) * cpx + (bid >> 3);
    int bm = (int)(bid / nTn) * 256;
    int bn = (int)(bid % nTn) * 256;

    int tid = threadIdx.x;
    int wave = tid >> 6;
    int lane = tid & 63;
    int wm = wave >> 2;                   // 0..1
    int wn = wave & 3;                    // 0..3
    int lr = lane & 15;
    int cg = lane >> 4;                   // chunk group 0..3
    int cofs = ((cg ^ ((lr >> 1) & 3)) << 3);   // swizzled chunk offset (halfs)

    f32x4 acc[8][4];
#pragma unroll
    for (int i = 0; i < 8; ++i)
#pragma unroll
        for (int j = 0; j < 4; ++j) acc[i][j] = (f32x4){0.f, 0.f, 0.f, 0.f};
    half8 bfr[4];

    // prologue: kt0 fully (8 loads), kt1 B0/A0/B1 (6 loads); kt1 A1 at ph1
    stage_q(B, K,   bn, 0,  &lds[0][1][0][0], tid, wave);
    stage_q(A, lda, bm, 0,  &lds[0][0][0][0], tid, wave);
    stage_q(B, K,   bn, 32, &lds[0][1][1][0], tid, wave);
    stage_q(A, lda, bm, 32, &lds[0][0][1][0], tid, wave);
    stage_q(B, K,   bn, 64, &lds[1][1][0][0], tid, wave);
    stage_q(A, lda, bm, 64, &lds[1][0][0][0], tid, wave);
    stage_q(B, K,   bn, 96, &lds[1][1][1][0], tid, wave);
    asm volatile("s_waitcnt vmcnt(6)" ::: "memory");
    __builtin_amdgcn_s_barrier();

    int NI = K >> 7;                      // 2 K-tiles per iteration
    for (int it = 0; it < NI; ++it) {
        int gk = it << 7;
        bool last = (it == NI - 1);
        // --- K-tile kt0 = 2it (buf 0) ---
        PH(0, 0, 0, true,
           { stage_q(A, lda, bm, gk + 96, &lds[1][0][1][0], tid, wave); }, {});
        PH(0, 0, 1, false,
           { if (!last) stage_q(B, K, bn, gk + 128, &lds[0][1][0][0], tid, wave); }, {});
        PH(0, 1, 0, true,
           { if (!last) stage_q(A, lda, bm, gk + 128, &lds[0][0][0][0], tid, wave); }, {});
        PH(0, 1, 1, false,
           { if (!last) stage_q(B, K, bn, gk + 160, &lds[0][1][1][0], tid, wave); },
           { if (last) asm volatile("s_waitcnt vmcnt(0)" ::: "memory");
             else      asm volatile("s_waitcnt vmcnt(6)" ::: "memory"); });
        // --- K-tile kt1 = 2it+1 (buf 1) ---
        PH(1, 0, 0, true,
           { if (!last) stage_q(A, lda, bm, gk + 160, &lds[0][0][1][0], tid, wave); }, {});
        PH(1, 0, 1, false,
           { if (!last) stage_q(B, K, bn, gk + 192, &lds[1][1][0][0], tid, wave); }, {});
        PH(1, 1, 0, true,
           { if (!last) stage_q(A, lda, bm, gk + 192, &lds[1][0][0][0], tid, wave); }, {});
        PH(1, 1, 1, false,
           { if (!last) stage_q(B, K, bn, gk + 224, &lds[1][1][1][0], tid, wave); },
           { if (!last) asm volatile("s_waitcnt vmcnt(6)" ::: "memory"); });
    }

    int orow0 = bm + wm * 128 + (lane >> 4) * 4;
    int ocol0 = bn + wn * 64 + lr;
#pragma unroll
    for (int mf = 0; mf < 8; ++mf)
#pragma unroll
        for (int nj = 0; nj < 4; ++nj)
#pragma unroll
            for (int r = 0; r < 4; ++r)
                C[(size_t)(orow0 + mf * 16 + r) * ldc + (ocol0 + nj * 16)] =
                    (OutT)acc[mf][nj][r];
}

// ---------------------------------------------------------------------------
// x_dbl = x_conv @ Wh^T  (M=16384, N=48 padded from 33, K=2048) via MFMA.
// ---------------------------------------------------------------------------
__global__ __launch_bounds__(256, 2)
void xdbl_mfma_k(const f16* __restrict__ xc, const f16* __restrict__ Wh,
                 float* __restrict__ xdbl) {
    __shared__ f16 As[64 * 64];   // 8 KB
    __shared__ f16 Bs[48 * 64];   // 6 KB
    int bm = blockIdx.x * 64;
    int tid = threadIdx.x;
    int wave = tid >> 6;
    int lane = tid & 63;
    int srow = lane >> 3;
    int scol = (lane & 7) * 8;
    int lr = lane & 15;
    int lkh = (lane >> 4) * 8;

    f32x4 acc[3];
#pragma unroll
    for (int j = 0; j < 3; ++j) acc[j] = (f32x4){0.f, 0.f, 0.f, 0.f};

    for (int k0 = 0; k0 < 2048; k0 += 64) {
        __syncthreads();
#pragma unroll
        for (int i = 0; i < 2; ++i) {
            int slot = wave * 2 + i;
            gload_lds16(xc + (size_t)(bm + slot * 8 + srow) * 2048 + (k0 + scol),
                        As + slot * 512);
        }
        if (wave < 3) {
#pragma unroll
            for (int i = 0; i < 2; ++i) {
                int slot = wave * 2 + i;
                gload_lds16(Wh + (size_t)(slot * 8 + srow) * 2048 + (k0 + scol),
                            Bs + slot * 512);
            }
        }
        asm volatile("s_waitcnt vmcnt(0)" ::: "memory");
        __syncthreads();
#pragma unroll
        for (int kk = 0; kk < 2; ++kk) {
            half8 a = *(const half8*)(As + (wave * 16 + lr) * 64 + kk * 32 + lkh);
#pragma unroll
            for (int nj = 0; nj < 3; ++nj) {
                half8 b = *(const half8*)(Bs + (nj * 16 + lr) * 64 + kk * 32 + lkh);
                acc[nj] = __builtin_amdgcn_mfma_f32_16x16x32_f16(a, b, acc[nj], 0, 0, 0);
            }
        }
    }

    int orow0 = bm + wave * 16 + (lane >> 4) * 4;
#pragma unroll
    for (int nj = 0; nj < 3; ++nj) {
        int col = nj * 16 + lr;
        if (col < 33) {
#pragma unroll
            for (int r = 0; r < 4; ++r)
                xdbl[(size_t)(orow0 + r) * 33 + col] = acc[nj][r];
        }
    }
}

// ---------------------------------------------------------------------------
// Depthwise causal conv (k=4) + bias + SiLU.
// 8 output rows per block (grid 2048), sliding 11-row register window:
// read amplification 11/8 = 1.375x (was 4x with 1 row/block).
// 4096 % 8 == 0 so a block never crosses a batch boundary.
// ---------------------------------------------------------------------------
__global__ __launch_bounds__(256)
void conv_silu_k(const f16* __restrict__ xz, const float* __restrict__ cw,
                 const float* __restrict__ cb, f16* __restrict__ xc) {
    int r0 = blockIdx.x * 8;     // first output row (0..16376)
    int d0 = threadIdx.x << 3;   // 0..2040
    int l0 = r0 & 4095;          // position within batch

    const float4* cw4 = (const float4*)cw;
    float4 w[8];
    float bias[8];
#pragma unroll
    for (int e = 0; e < 8; ++e) { w[e] = cw4[d0 + e]; bias[e] = cb[d0 + e]; }

    half8 xv[11];
#pragma unroll
    for (int j = 0; j < 11; ++j) {
        if (l0 - 3 + j >= 0)
            xv[j] = *(const half8*)(xz + (size_t)(r0 - 3 + j) * 4096 + d0);
        else
            xv[j] = (half8){};
    }

#pragma unroll
    for (int rr = 0; rr < 8; ++rr) {
        float acc[8];
#pragma unroll
        for (int e = 0; e < 8; ++e) acc[e] = bias[e];
#pragma unroll
        for (int k = 0; k < 4; ++k) {
            half8 xk = xv[rr + k];
#pragma unroll
            for (int e = 0; e < 8; ++e) {
                float wj = (k == 0) ? w[e].x : (k == 1) ? w[e].y : (k == 2) ? w[e].z : w[e].w;
                acc[e] = fmaf((float)xk[e], wj, acc[e]);
            }
        }
        half8 out = {};
#pragma unroll
        for (int e = 0; e < 8; ++e) {
            float v = acc[e];
            out[e] = (f16)(v / (1.f + expf(-v)));
        }
        *(half8*)(xc + (size_t)(r0 + rr) * 2048 + d0) = out;
    }
}

// ---------------------------------------------------------------------------
// SP[m][48] = { dA[16]=exp(A_n*delta), dB[16]=delta*B, C[16] }, delta out
// ---------------------------------------------------------------------------
__global__ __launch_bounds__(256)
void sp_build_k(const float* __restrict__ xdbl, const float* __restrict__ A_log,
                float* __restrict__ SP, float* __restrict__ dlt) {
    int m = blockIdx.x * 256 + threadIdx.x;
    const float* row = xdbl + (size_t)m * 33;
    float v0 = row[0];
    float d = (v0 > 15.f) ? v0 : logf(1.f + expf(v0));  // softplus
    dlt[m] = d;
    float* sp = SP + (size_t)m * 48;
#pragma unroll
    for (int n = 0; n < 16; ++n) {
        float An = -expf(A_log[n]);
        sp[n] = expf(An * d);
        sp[16 + n] = d * row[1 + n];
        sp[32 + n] = row[17 + n];
    }
}

// ---------------------------------------------------------------------------
// G[bc][n] = exp(A_n * sum_{t in chunk} delta)   (T=128 chunks)
// ---------------------------------------------------------------------------
__global__ __launch_bounds__(128)
void g_build_k(const float* __restrict__ dlt, const float* __restrict__ A_log,
               float* __restrict__ G) {
    __shared__ float red[128];
    int bc = blockIdx.x, t = threadIdx.x;
    red[t] = dlt[bc * 128 + t];
    __syncthreads();
#pragma unroll
    for (int s = 64; s > 0; s >>= 1) {
        if (t < s) red[t] += red[t + s];
        __syncthreads();
    }
    if (t < 16) G[bc * 16 + t] = expf(-expf(A_log[t]) * red[0]);
}

// ---------------------------------------------------------------------------
// Scan pass 1 (T=128): per (b,c,d) local scan with h0=0; write final state F.
// blk = (bc*8 + dg); SP chunk (24 KB) staged in LDS -> 4+ blocks/CU.
// ---------------------------------------------------------------------------
__global__ __launch_bounds__(256)
void scan1_k(const f16* __restrict__ xc, const float* __restrict__ SP,
             float* __restrict__ F) {
    __shared__ float sp[128 * 48];
    int blk = blockIdx.x;
    int dg = blk & 7;
    int bc = blk >> 3;               // chunk 0..127
    int tid = threadIdx.x;
    int wave = tid >> 6;
    int d = dg * 256 + tid;
    int mbase = bc * 128;

    const char* spb = (const char*)(SP + (size_t)mbase * 48);
#pragma unroll
    for (int i = 0; i < 6; ++i)
        gload_lds16(spb + (size_t)(i * 256 + tid) * 16,
                    (char*)sp + (size_t)(i * 256 + wave * 64) * 16);
    asm volatile("s_waitcnt vmcnt(0)" ::: "memory");
    __syncthreads();

    float h[16];
#pragma unroll
    for (int n = 0; n < 16; ++n) h[n] = 0.f;

#pragma unroll 2
    for (int tt = 0; tt < 128; ++tt) {
        const float* r = sp + tt * 48;
        float x = (float)xc[(size_t)(mbase + tt) * 2048 + d];
#pragma unroll
        for (int n = 0; n < 16; ++n) h[n] = fmaf(h[n], r[n], x * r[16 + n]);
    }
    size_t fb = ((size_t)bc * 2048 + d) * 16;
#pragma unroll
    for (int n = 0; n < 16; ++n) F[fb + n] = h[n];
}

// ---------------------------------------------------------------------------
// Combine: sequential over 32 chunks per (b,d) chain: H0[c]=state before c.
// ---------------------------------------------------------------------------
__global__ __launch_bounds__(256)
void combine_k(const float* __restrict__ F, const float* __restrict__ G,
               float* __restrict__ H0) {
    int gid = blockIdx.x * 256 + threadIdx.x;  // 8192 chains
    int b = gid >> 11;
    int d = gid & 2047;
    float h[16];
#pragma unroll
    for (int n = 0; n < 16; ++n) h[n] = 0.f;
    for (int c = 0; c < 32; ++c) {
        int bc = b * 32 + c;
        size_t base = ((size_t)bc * 2048 + d) * 16;
#pragma unroll
        for (int n = 0; n < 16; ++n) H0[base + n] = h[n];
#pragma unroll
        for (int n = 0; n < 16; ++n) h[n] = fmaf(G[bc * 16 + n], h[n], F[base + n]);
    }
}

// ---------------------------------------------------------------------------
// Scan pass 2 (T=128): replay with correct h0, emit y=(scan_y+x*D)*silu(z).
// ---------------------------------------------------------------------------
__global__ __launch_bounds__(256)
void scan2_k(const f16* __restrict__ xc, const f16* xz, const float* __restrict__ SP,
             const float* __restrict__ H0, const float* __restrict__ Dv,
             f16* yout) {
    __shared__ float sp[128 * 48];
    int blk = blockIdx.x;
    int dg = blk & 7;
    int bc = blk >> 3;
    int tid = threadIdx.x;
    int wave = tid >> 6;
    int d = dg * 256 + tid;
    int mbase = bc * 128;

    const char* spb = (const char*)(SP + (size_t)mbase * 48);
#pragma unroll
    for (int i = 0; i < 6; ++i)
        gload_lds16(spb + (size_t)(i * 256 + tid) * 16,
                    (char*)sp + (size_t)(i * 256 + wave * 64) * 16);
    asm volatile("s_waitcnt vmcnt(0)" ::: "memory");
    __syncthreads();

    size_t fb = ((size_t)bc * 2048 + d) * 16;
    float h[16];
#pragma unroll
    for (int n = 0; n < 16; ++n) h[n] = H0[fb + n];
    float Dd = Dv[d];

#pragma unroll 2
    for (int tt = 0; tt < 128; ++tt) {
        const float* r = sp + tt * 48;
        size_t mrow = (size_t)(mbase + tt);
        float x = (float)xc[mrow * 2048 + d];
        float z = (float)xz[mrow * 4096 + 2048 + d];
        float y0 = 0.f, y1 = 0.f, y2 = 0.f, y3 = 0.f;
#pragma unroll
        for (int n = 0; n < 16; n += 4) {
            h[n]     = fmaf(h[n],     r[n],     x * r[16 + n]);
            h[n + 1] = fmaf(h[n + 1], r[n + 1], x * r[17 + n]);
            h[n + 2] = fmaf(h[n + 2], r[n + 2], x * r[18 + n]);
            h[n + 3] = fmaf(h[n + 3], r[n + 3], x * r[19 + n]);
            y0 = fmaf(h[n],     r[32 + n], y0);
            y1 = fmaf(h[n + 1], r[33 + n], y1);
            y2 = fmaf(h[n + 2], r[34 + n], y2);
            y3 = fmaf(h[n + 3], r[35 + n], y3);
        }
        float y = (y0 + y1) + (y2 + y3);
        float yf = fmaf(x, Dd, y);
        float sz = z / (1.f + expf(-z));
        yout[mrow * 4096 + d] = (f16)(yf * sz);
    }
}

// ---------------------------------------------------------------------------
// Workspace layout (aliased by lifetime; peak 240,459,776 B ~= 229 MiB):
//   [0,   134217728)  xzh  : f16 16384x4096 (x_inner|z; x_inner cols become y)
//   [134217728, +67108864) region1:
//        phase A (cvt+GEMM1):  xh f16 16384x1024 @ +0, wih f16 4096x1024 @ +33554432
//        phase B (conv..scan2): xch f16 16384x2048 @ +0
//        phase C (final GEMM):  woh f16 1024x2048 @ +0  (converted after scan2)
//   [201326592, ...)  xdbl(2162688) dlt(65536) SP(3145728) G(8192)
//                     F(16777216) H0(16777216) Wh(196608)  end = 240459776
// ---------------------------------------------------------------------------
extern "C" void kernel_launch(void* const* d_in, const int* in_sizes, int n_in,
                              void* d_out, int out_size, void* d_ws, size_t ws_size,
                              hipStream_t stream) {
    const float* x      = (const float*)d_in[0];
    const float* w_in   = (const float*)d_in[1];
    const float* conv_w = (const float*)d_in[2];
    const float* conv_b = (const float*)d_in[3];
    const float* w_xp   = (const float*)d_in[4];
    const float* A_log  = (const float*)d_in[5];
    const float* Dv     = (const float*)d_in[6];
    const float* w_out  = (const float*)d_in[7];

    char* base = (char*)d_ws;
    f16* xzh = (f16*)base;                          // 134217728 B
    char* r1 = base + 134217728;                    // 67108864 B shared region
    f16* xh  = (f16*)r1;                            // 33554432 B   (phase A)
    f16* wih = (f16*)(r1 + 33554432);               // 8388608 B    (phase A)
    f16* xch = (f16*)r1;                            // 67108864 B   (phase B)
    f16* woh = (f16*)r1;                            // 4194304 B    (phase C)
    char* p = base + 201326592;
    float* xdbl = (float*)p;  p += 2162688;         // 16384x33
    float* dlt  = (float*)p;  p += 65536;           // 16384
    float* SP   = (float*)p;  p += 3145728;         // 16384x48
    float* G    = (float*)p;  p += 8192;            // 128x16
    float* F    = (float*)p;  p += 16777216;        // 128x2048x16
    float* H0   = (float*)p;  p += 16777216;        // 128x2048x16
    f16*   Wh   = (f16*)p;    p += 196608;          // 48x2048 f16 padded x_proj_w

    // dtype conversions for GEMM1 + padded x_proj_w
    cvt_f16_k<<<2048, 256, 0, stream>>>(x, xh, 4194304);
    cvt_f16_k<<<2048, 256, 0, stream>>>(w_in, wih, 1048576);
    wxp_cvt_k<<<384, 256, 0, stream>>>(w_xp, Wh);

    // xz = x @ in_proj_w^T   (M=16384, N=4096, K=1024) — 8-phase 256² template
    gemm8p<f16><<<1024, 512, 0, stream>>>(xh, wih, xzh, 4096, 1024, 1024, 4096);

    // depthwise conv + SiLU -> x_conv   (xh/wih dead; xch overlays them)
    conv_silu_k<<<2048, 256, 0, stream>>>(xzh, conv_w, conv_b, xch);

    // x_dbl = x_conv @ x_proj_w^T  (N=33 padded to 48) via MFMA
    xdbl_mfma_k<<<256, 256, 0, stream>>>(xch, Wh, xdbl);

    // per-(b,t) scan coefficients
    sp_build_k<<<64, 256, 0, stream>>>(xdbl, A_log, SP, dlt);
    g_build_k<<<128, 128, 0, stream>>>(dlt, A_log, G);

    // chunked selective scan (T=128, 32 chunks/batch)
    scan1_k<<<1024, 256, 0, stream>>>(xch, SP, F);
    combine_k<<<32, 256, 0, stream>>>(F, G, H0);
    scan2_k<<<1024, 256, 0, stream>>>(xch, xzh, SP, H0, Dv, xzh);

    // convert out_proj_w late (xch dead; woh overlays region1)
    cvt_f16_k<<<2048, 256, 0, stream>>>(w_out, woh, 524288);

    // out = y @ out_proj_w^T  (M=16384, N=1024, K=2048, lda=4096, fp32 out)
    gemm8p<float><<<256, 512, 0, stream>>>(xzh, woh, (float*)d_out,
                                           1024, 2048, 4096, 1024);
}

// Round 6
// 446.121 us; speedup vs baseline: 2.0450x; 1.0840x over previous
//
#include <hip/hip_runtime.h>
#include <hip/hip_fp16.h>

typedef _Float16 f16;
typedef _Float16 half8 __attribute__((ext_vector_type(8)));
typedef _Float16 half4v __attribute__((ext_vector_type(4)));
typedef float f32x4 __attribute__((ext_vector_type(4)));

#define AS1(p) ((const __attribute__((address_space(1))) void*)(p))
#define AS3(p) ((__attribute__((address_space(3))) void*)(p))

__device__ __forceinline__ void gload_lds16(const void* g, void* l) {
    __builtin_amdgcn_global_load_lds(AS1(g), AS3(l), 16, 0, 0);
}

// ---------------------------------------------------------------------------
// Fused input conversions: x (f32->f16), in_proj_w (f32->f16),
// x_proj_w (33x2048 f32 -> zero-padded 48x2048 f16).  Grid 2944.
// ---------------------------------------------------------------------------
__global__ __launch_bounds__(256)
void prep_k(const float* __restrict__ x, const float* __restrict__ w_in,
            const float* __restrict__ w_xp,
            f16* __restrict__ xh, f16* __restrict__ wih, f16* __restrict__ Wh) {
    int b = blockIdx.x;
    if (b < 2048) {
        for (int i = b * 256 + threadIdx.x; i < 4194304; i += 2048 * 256) {
            float4 v = ((const float4*)x)[i];
            half4v o; o[0] = (f16)v.x; o[1] = (f16)v.y; o[2] = (f16)v.z; o[3] = (f16)v.w;
            ((half4v*)xh)[i] = o;
        }
    } else if (b < 2560) {
        for (int i = (b - 2048) * 256 + threadIdx.x; i < 1048576; i += 512 * 256) {
            float4 v = ((const float4*)w_in)[i];
            half4v o; o[0] = (f16)v.x; o[1] = (f16)v.y; o[2] = (f16)v.z; o[3] = (f16)v.w;
            ((half4v*)wih)[i] = o;
        }
    } else {
        int idx = (b - 2560) * 256 + threadIdx.x;   // 0..98303
        int e = idx >> 11;
        int k = idx & 2047;
        Wh[idx] = (e < 33) ? (f16)w_xp[e * 2048 + k] : (f16)0.f;
    }
}

// ---------------------------------------------------------------------------
// f32 -> f16 conversion (vectorized x4, grid-stride)  (out_proj_w, late)
// ---------------------------------------------------------------------------
__global__ __launch_bounds__(256) void cvt_f16_k(const float* __restrict__ in,
                                                 f16* __restrict__ out, int n4) {
    for (int i = blockIdx.x * 256 + threadIdx.x; i < n4; i += gridDim.x * 256) {
        float4 v = ((const float4*)in)[i];
        half4v o;
        o[0] = (f16)v.x; o[1] = (f16)v.y; o[2] = (f16)v.z; o[3] = (f16)v.w;
        ((half4v*)out)[i] = o;
    }
}

// ===========================================================================
// Persistent 256x256 8-phase GEMM (T1+T2+T3+T4+T5), f16 MFMA 16x16x32.
// C[M,N] = A[M,K(lda)] * B[N,K]^T.  BK=64, 8 waves (2Mx4N), 512 threads.
// NT tiles per block, grid = totalTiles/NT (1 round, 1 block/CU at 128KiB).
//
// Bridging: the last iteration of tile j stages tile j+1's first 7 quarters
// in the SAME phase->slot pattern as the steady state (ph2..ph8 stage
// B k0, A k0, B k32, A k32, B k64, A k64, B k96 -> slots [0][1][0],[0][0][0],
// [0][1][1],[0][0][1],[1][1][0],[1][0][0],[1][1][1]), which is exactly the
// prologue.  All last-read/overwrite pairs and vmcnt(6) windows are therefore
// identical to the steady loop (verified slot-by-slot).  The C-store epilogue
// (regs only, no LDS) sits between ph8's barrier and the next ph1; the
// following vmcnt(6) conservatively also drains those stores (correct, minor).
// Quarter layout: [256 rows][32 halfs], chunk swizzle chunk^=(row>>1)&3
// (both-sides involution; bank-conflict-free, measured 0).
// ===========================================================================
__device__ __forceinline__ void stage_q(const f16* __restrict__ g, int ld,
                                        int row0, int gk, f16* q,
                                        int tid, int wave) {
#pragma unroll
    for (int rd = 0; rd < 2; ++rd) {
        int t = rd * 512 + tid;
        int r = t >> 2;                       // row 0..255
        int cu = (t & 3) ^ ((r >> 1) & 3);    // unswizzled chunk for this slot
        gload_lds16(g + (size_t)(row0 + r) * ld + gk + cu * 8,
                    q + rd * 4096 + wave * 512);   // wave-uniform linear dest
    }
}

#define PH(Q, KH, MH, LOADB, STAGE, WAITC)                                    \
  {                                                                           \
    half8 afr[4];                                                             \
    {                                                                         \
      const f16* aq = &lds[Q][0][KH][0];                                      \
      int ra = wm * 128 + (MH) * 64 + lr;                                     \
      afr[0] = *(const half8*)(aq + (ra +  0) * 32 + cofs);                   \
      afr[1] = *(const half8*)(aq + (ra + 16) * 32 + cofs);                   \
      afr[2] = *(const half8*)(aq + (ra + 32) * 32 + cofs);                   \
      afr[3] = *(const half8*)(aq + (ra + 48) * 32 + cofs);                   \
    }                                                                         \
    if (LOADB) {                                                              \
      const f16* bq = &lds[Q][1][KH][0];                                      \
      int rb = wn * 64 + lr;                                                  \
      bfr[0] = *(const half8*)(bq + (rb +  0) * 32 + cofs);                   \
      bfr[1] = *(const half8*)(bq + (rb + 16) * 32 + cofs);                   \
      bfr[2] = *(const half8*)(bq + (rb + 32) * 32 + cofs);                   \
      bfr[3] = *(const half8*)(bq + (rb + 48) * 32 + cofs);                   \
    }                                                                         \
    STAGE;                                                                    \
    __builtin_amdgcn_s_barrier();                                             \
    asm volatile("s_waitcnt lgkmcnt(0)" ::: "memory");                        \
    __builtin_amdgcn_sched_barrier(0);                                        \
    __builtin_amdgcn_s_setprio(1);                                            \
    _Pragma("unroll")                                                         \
    for (int f_ = 0; f_ < 4; ++f_)                                            \
      _Pragma("unroll")                                                       \
      for (int j_ = 0; j_ < 4; ++j_)                                          \
        acc[(MH) * 4 + f_][j_] = __builtin_amdgcn_mfma_f32_16x16x32_f16(      \
            afr[f_], bfr[j_], acc[(MH) * 4 + f_][j_], 0, 0, 0);               \
    __builtin_amdgcn_s_setprio(0);                                            \
    __builtin_amdgcn_sched_barrier(0);                                        \
    WAITC;                                                                    \
    __builtin_amdgcn_s_barrier();                                             \
  }

template <typename OutT, int NT>
__global__ __launch_bounds__(512, 2)
void gemm8p_pers(const f16* __restrict__ A, const f16* __restrict__ B,
                 OutT* __restrict__ C, int N, int K, int lda, int ldc) {
    __shared__ f16 lds[2][2][2][8192];   // [buf][A/B][kh][quarter] = 128 KiB

    int nTn = N >> 8;
    unsigned grid = gridDim.x;
    unsigned cpx = (grid * (unsigned)NT) >> 3;   // XCD chunk size (bijective)

    int tid = threadIdx.x;
    int wave = tid >> 6;
    int lane = tid & 63;
    int wm = wave >> 2;                   // 0..1
    int wn = wave & 3;                    // 0..3
    int lr = lane & 15;
    int cg = lane >> 4;                   // chunk group 0..3
    int cofs = ((cg ^ ((lr >> 1) & 3)) << 3);   // swizzled chunk offset (halfs)

    f32x4 acc[8][4];
#pragma unroll
    for (int i = 0; i < 8; ++i)
#pragma unroll
        for (int j = 0; j < 4; ++j) acc[i][j] = (f32x4){0.f, 0.f, 0.f, 0.f};
    half8 bfr[4];

    // tile j -> (bm,bn):  orig = blockIdx + grid*j keeps XCD fixed (grid%8==0)
    auto tileMN = [&](int j, int& tm, int& tn) {
        unsigned o = blockIdx.x + grid * (unsigned)j;
        unsigned s = (o & 7u) * cpx + (o >> 3);
        tm = (int)(s / (unsigned)nTn) * 256;
        tn = (int)(s % (unsigned)nTn) * 256;
    };

    int bm, bn;
    tileMN(0, bm, bn);

    // prologue: kt0 fully (8 loads), kt1 B0/A0/B1 (6 loads); kt1 A1 at ph1
    stage_q(B, K,   bn, 0,  &lds[0][1][0][0], tid, wave);
    stage_q(A, lda, bm, 0,  &lds[0][0][0][0], tid, wave);
    stage_q(B, K,   bn, 32, &lds[0][1][1][0], tid, wave);
    stage_q(A, lda, bm, 32, &lds[0][0][1][0], tid, wave);
    stage_q(B, K,   bn, 64, &lds[1][1][0][0], tid, wave);
    stage_q(A, lda, bm, 64, &lds[1][0][0][0], tid, wave);
    stage_q(B, K,   bn, 96, &lds[1][1][1][0], tid, wave);
    asm volatile("s_waitcnt vmcnt(6)" ::: "memory");
    __builtin_amdgcn_s_barrier();

    int NI = K >> 7;                      // 2 K-tiles per iteration
    for (int j = 0; j < NT; ++j) {
        int bm2 = bm, bn2 = bn;
        if (j + 1 < NT) tileMN(j + 1, bm2, bn2);

        for (int it = 0; it < NI; ++it) {
            int gk = it << 7;
            bool lastIter = (it == NI - 1);
            bool fin = lastIter && (j + 1 == NT);   // absolute end
            // stage source for the "+128..+224" slots: next tile when bridging
            int sbm = lastIter ? bm2 : bm;
            int sbn = lastIter ? bn2 : bn;
            int sgk = lastIter ? 0 : gk + 128;

            // --- K-tile kt0 (buf 0) ---
            PH(0, 0, 0, true,
               { stage_q(A, lda, bm, gk + 96, &lds[1][0][1][0], tid, wave); }, {});
            PH(0, 0, 1, false,
               { if (!fin) stage_q(B, K, sbn, sgk, &lds[0][1][0][0], tid, wave); }, {});
            PH(0, 1, 0, true,
               { if (!fin) stage_q(A, lda, sbm, sgk, &lds[0][0][0][0], tid, wave); }, {});
            PH(0, 1, 1, false,
               { if (!fin) stage_q(B, K, sbn, sgk + 32, &lds[0][1][1][0], tid, wave); },
               { if (fin) asm volatile("s_waitcnt vmcnt(0)" ::: "memory");
                 else     asm volatile("s_waitcnt vmcnt(6)" ::: "memory"); });
            // --- K-tile kt1 (buf 1) ---
            PH(1, 0, 0, true,
               { if (!fin) stage_q(A, lda, sbm, sgk + 32, &lds[0][0][1][0], tid, wave); }, {});
            PH(1, 0, 1, false,
               { if (!fin) stage_q(B, K, sbn, sgk + 64, &lds[1][1][0][0], tid, wave); }, {});
            PH(1, 1, 0, true,
               { if (!fin) stage_q(A, lda, sbm, sgk + 64, &lds[1][0][0][0], tid, wave); }, {});
            PH(1, 1, 1, false,
               { if (!fin) stage_q(B, K, sbn, sgk + 96, &lds[1][1][1][0], tid, wave); },
               { if (!fin) asm volatile("s_waitcnt vmcnt(6)" ::: "memory"); });
        }

        // epilogue tile j (registers only; no LDS -> safe vs in-flight stages)
        int orow0 = bm + wm * 128 + (lane >> 4) * 4;
        int ocol0 = bn + wn * 64 + lr;
#pragma unroll
        for (int mf = 0; mf < 8; ++mf)
#pragma unroll
            for (int nj = 0; nj < 4; ++nj)
#pragma unroll
                for (int r = 0; r < 4; ++r)
                    C[(size_t)(orow0 + mf * 16 + r) * ldc + (ocol0 + nj * 16)] =
                        (OutT)acc[mf][nj][r];
#pragma unroll
        for (int i2 = 0; i2 < 8; ++i2)
#pragma unroll
            for (int j2 = 0; j2 < 4; ++j2) acc[i2][j2] = (f32x4){0.f, 0.f, 0.f, 0.f};
        bm = bm2; bn = bn2;
    }
}

// ---------------------------------------------------------------------------
// x_dbl = x_conv @ Wh^T  (M=16384, N=48 padded from 33, K=2048) via MFMA.
// ---------------------------------------------------------------------------
__global__ __launch_bounds__(256, 2)
void xdbl_mfma_k(const f16* __restrict__ xc, const f16* __restrict__ Wh,
                 float* __restrict__ xdbl) {
    __shared__ f16 As[64 * 64];   // 8 KB
    __shared__ f16 Bs[48 * 64];   // 6 KB
    int bm = blockIdx.x * 64;
    int tid = threadIdx.x;
    int wave = tid >> 6;
    int lane = tid & 63;
    int srow = lane >> 3;
    int scol = (lane & 7) * 8;
    int lr = lane & 15;
    int lkh = (lane >> 4) * 8;

    f32x4 acc[3];
#pragma unroll
    for (int j = 0; j < 3; ++j) acc[j] = (f32x4){0.f, 0.f, 0.f, 0.f};

    for (int k0 = 0; k0 < 2048; k0 += 64) {
        __syncthreads();
#pragma unroll
        for (int i = 0; i < 2; ++i) {
            int slot = wave * 2 + i;
            gload_lds16(xc + (size_t)(bm + slot * 8 + srow) * 2048 + (k0 + scol),
                        As + slot * 512);
        }
        if (wave < 3) {
#pragma unroll
            for (int i = 0; i < 2; ++i) {
                int slot = wave * 2 + i;
                gload_lds16(Wh + (size_t)(slot * 8 + srow) * 2048 + (k0 + scol),
                            Bs + slot * 512);
            }
        }
        asm volatile("s_waitcnt vmcnt(0)" ::: "memory");
        __syncthreads();
#pragma unroll
        for (int kk = 0; kk < 2; ++kk) {
            half8 a = *(const half8*)(As + (wave * 16 + lr) * 64 + kk * 32 + lkh);
#pragma unroll
            for (int nj = 0; nj < 3; ++nj) {
                half8 b = *(const half8*)(Bs + (nj * 16 + lr) * 64 + kk * 32 + lkh);
                acc[nj] = __builtin_amdgcn_mfma_f32_16x16x32_f16(a, b, acc[nj], 0, 0, 0);
            }
        }
    }

    int orow0 = bm + wave * 16 + (lane >> 4) * 4;
#pragma unroll
    for (int nj = 0; nj < 3; ++nj) {
        int col = nj * 16 + lr;
        if (col < 33) {
#pragma unroll
            for (int r = 0; r < 4; ++r)
                xdbl[(size_t)(orow0 + r) * 33 + col] = acc[nj][r];
        }
    }
}

// ---------------------------------------------------------------------------
// Depthwise causal conv (k=4) + bias + SiLU.  8 rows/block, sliding window.
// ---------------------------------------------------------------------------
__global__ __launch_bounds__(256)
void conv_silu_k(const f16* __restrict__ xz, const float* __restrict__ cw,
                 const float* __restrict__ cb, f16* __restrict__ xc) {
    int r0 = blockIdx.x * 8;     // first output row (0..16376)
    int d0 = threadIdx.x << 3;   // 0..2040
    int l0 = r0 & 4095;          // position within batch

    const float4* cw4 = (const float4*)cw;
    float4 w[8];
    float bias[8];
#pragma unroll
    for (int e = 0; e < 8; ++e) { w[e] = cw4[d0 + e]; bias[e] = cb[d0 + e]; }

    half8 xv[11];
#pragma unroll
    for (int j = 0; j < 11; ++j) {
        if (l0 - 3 + j >= 0)
            xv[j] = *(const half8*)(xz + (size_t)(r0 - 3 + j) * 4096 + d0);
        else
            xv[j] = (half8){};
    }

#pragma unroll
    for (int rr = 0; rr < 8; ++rr) {
        float acc[8];
#pragma unroll
        for (int e = 0; e < 8; ++e) acc[e] = bias[e];
#pragma unroll
        for (int k = 0; k < 4; ++k) {
            half8 xk = xv[rr + k];
#pragma unroll
            for (int e = 0; e < 8; ++e) {
                float wj = (k == 0) ? w[e].x : (k == 1) ? w[e].y : (k == 2) ? w[e].z : w[e].w;
                acc[e] = fmaf((float)xk[e], wj, acc[e]);
            }
        }
        half8 out = {};
#pragma unroll
        for (int e = 0; e < 8; ++e) {
            float v = acc[e];
            out[e] = (f16)(v / (1.f + expf(-v)));
        }
        *(half8*)(xc + (size_t)(r0 + rr) * 2048 + d0) = out;
    }
}

// ---------------------------------------------------------------------------
// Fused SP-build + chunk-transition G (T=128): one block per chunk.
// SP[m][48] = { exp(A_n*delta), delta*B, C };  G[bc][n]=exp(A_n*sum delta)
// ---------------------------------------------------------------------------
__global__ __launch_bounds__(128)
void spg_k(const float* __restrict__ xdbl, const float* __restrict__ A_log,
           float* __restrict__ SP, float* __restrict__ G) {
    __shared__ float red[128];
    int bc = blockIdx.x;               // chunk 0..127
    int t = threadIdx.x;               // m within chunk
    int m = bc * 128 + t;
    const float* row = xdbl + (size_t)m * 33;
    float v0 = row[0];
    float d = (v0 > 15.f) ? v0 : logf(1.f + expf(v0));  // softplus
    float* sp = SP + (size_t)m * 48;
#pragma unroll
    for (int n = 0; n < 16; ++n) {
        float An = -expf(A_log[n]);
        sp[n] = expf(An * d);
        sp[16 + n] = d * row[1 + n];
        sp[32 + n] = row[17 + n];
    }
    red[t] = d;
    __syncthreads();
#pragma unroll
    for (int s = 64; s > 0; s >>= 1) {
        if (t < s) red[t] += red[t + s];
        __syncthreads();
    }
    if (t < 16) G[bc * 16 + t] = expf(-expf(A_log[t]) * red[0]);
}

// ---------------------------------------------------------------------------
// Scan pass 1 (T=128): per (b,c,d) local scan with h0=0; write final state F.
// ---------------------------------------------------------------------------
__global__ __launch_bounds__(256)
void scan1_k(const f16* __restrict__ xc, const float* __restrict__ SP,
             float* __restrict__ F) {
    __shared__ float sp[128 * 48];
    int blk = blockIdx.x;
    int dg = blk & 7;
    int bc = blk >> 3;               // chunk 0..127
    int tid = threadIdx.x;
    int wave = tid >> 6;
    int d = dg * 256 + tid;
    int mbase = bc * 128;

    const char* spb = (const char*)(SP + (size_t)mbase * 48);
#pragma unroll
    for (int i = 0; i < 6; ++i)
        gload_lds16(spb + (size_t)(i * 256 + tid) * 16,
                    (char*)sp + (size_t)(i * 256 + wave * 64) * 16);
    asm volatile("s_waitcnt vmcnt(0)" ::: "memory");
    __syncthreads();

    float h[16];
#pragma unroll
    for (int n = 0; n < 16; ++n) h[n] = 0.f;

#pragma unroll 2
    for (int tt = 0; tt < 128; ++tt) {
        const float* r = sp + tt * 48;
        float x = (float)xc[(size_t)(mbase + tt) * 2048 + d];
#pragma unroll
        for (int n = 0; n < 16; ++n) h[n] = fmaf(h[n], r[n], x * r[16 + n]);
    }
    size_t fb = ((size_t)bc * 2048 + d) * 16;
#pragma unroll
    for (int n = 0; n < 16; ++n) F[fb + n] = h[n];
}

// ---------------------------------------------------------------------------
// Combine: one thread per (b,d,n) scalar chain (131072 chains, 32 steps).
// F/H0 layout [bc][d][n] -> idx = bc*32768 + dn; coalesced across dn.
// ---------------------------------------------------------------------------
__global__ __launch_bounds__(256)
void combine_k(const float* __restrict__ F, const float* __restrict__ G,
               float* __restrict__ H0) {
    int gid = blockIdx.x * 256 + threadIdx.x;  // 0..131071
    int b = gid >> 15;
    int dn = gid & 32767;
    int n = dn & 15;
    float h = 0.f;
    for (int c = 0; c < 32; ++c) {
        int bc = b * 32 + c;
        size_t idx = (size_t)bc * 32768 + dn;
        H0[idx] = h;
        h = fmaf(G[bc * 16 + n], h, F[idx]);
    }
}

// ---------------------------------------------------------------------------
// Scan pass 2 (T=128): replay with correct h0, emit y=(scan_y+x*D)*silu(z).
// ---------------------------------------------------------------------------
__global__ __launch_bounds__(256)
void scan2_k(const f16* __restrict__ xc, const f16* xz, const float* __restrict__ SP,
             const float* __restrict__ H0, const float* __restrict__ Dv,
             f16* yout) {
    __shared__ float sp[128 * 48];
    int blk = blockIdx.x;
    int dg = blk & 7;
    int bc = blk >> 3;
    int tid = threadIdx.x;
    int wave = tid >> 6;
    int d = dg * 256 + tid;
    int mbase = bc * 128;

    const char* spb = (const char*)(SP + (size_t)mbase * 48);
#pragma unroll
    for (int i = 0; i < 6; ++i)
        gload_lds16(spb + (size_t)(i * 256 + tid) * 16,
                    (char*)sp + (size_t)(i * 256 + wave * 64) * 16);
    asm volatile("s_waitcnt vmcnt(0)" ::: "memory");
    __syncthreads();

    size_t fb = ((size_t)bc * 2048 + d) * 16;
    float h[16];
#pragma unroll
    for (int n = 0; n < 16; ++n) h[n] = H0[fb + n];
    float Dd = Dv[d];

#pragma unroll 2
    for (int tt = 0; tt < 128; ++tt) {
        const float* r = sp + tt * 48;
        size_t mrow = (size_t)(mbase + tt);
        float x = (float)xc[mrow * 2048 + d];
        float z = (float)xz[mrow * 4096 + 2048 + d];
        float y0 = 0.f, y1 = 0.f, y2 = 0.f, y3 = 0.f;
#pragma unroll
        for (int n = 0; n < 16; n += 4) {
            h[n]     = fmaf(h[n],     r[n],     x * r[16 + n]);
            h[n + 1] = fmaf(h[n + 1], r[n + 1], x * r[17 + n]);
            h[n + 2] = fmaf(h[n + 2], r[n + 2], x * r[18 + n]);
            h[n + 3] = fmaf(h[n + 3], r[n + 3], x * r[19 + n]);
            y0 = fmaf(h[n],     r[32 + n], y0);
            y1 = fmaf(h[n + 1], r[33 + n], y1);
            y2 = fmaf(h[n + 2], r[34 + n], y2);
            y3 = fmaf(h[n + 3], r[35 + n], y3);
        }
        float y = (y0 + y1) + (y2 + y3);
        float yf = fmaf(x, Dd, y);
        float sz = z / (1.f + expf(-z));
        yout[mrow * 4096 + d] = (f16)(yf * sz);
    }
}

// ---------------------------------------------------------------------------
// Workspace layout (aliased by lifetime; peak 240,459,776 B ~= 229 MiB):
//   [0,   134217728)  xzh  : f16 16384x4096 (x_inner|z; x_inner cols become y)
//   [134217728, +67108864) region1:
//        phase A (prep+GEMM1):  xh f16 16384x1024 @ +0, wih f16 4096x1024 @ +33554432
//        phase B (conv..scan2): xch f16 16384x2048 @ +0
//        phase C (final GEMM):  woh f16 1024x2048 @ +0  (converted after scan2)
//   [201326592, ...)  xdbl(2162688) [gap 65536] SP(3145728) G(8192)
//                     F(16777216) H0(16777216) Wh(196608)  end = 240459776
// ---------------------------------------------------------------------------
extern "C" void kernel_launch(void* const* d_in, const int* in_sizes, int n_in,
                              void* d_out, int out_size, void* d_ws, size_t ws_size,
                              hipStream_t stream) {
    const float* x      = (const float*)d_in[0];
    const float* w_in   = (const float*)d_in[1];
    const float* conv_w = (const float*)d_in[2];
    const float* conv_b = (const float*)d_in[3];
    const float* w_xp   = (const float*)d_in[4];
    const float* A_log  = (const float*)d_in[5];
    const float* Dv     = (const float*)d_in[6];
    const float* w_out  = (const float*)d_in[7];

    char* base = (char*)d_ws;
    f16* xzh = (f16*)base;                          // 134217728 B
    char* r1 = base + 134217728;                    // 67108864 B shared region
    f16* xh  = (f16*)r1;                            // 33554432 B   (phase A)
    f16* wih = (f16*)(r1 + 33554432);               // 8388608 B    (phase A)
    f16* xch = (f16*)r1;                            // 67108864 B   (phase B)
    f16* woh = (f16*)r1;                            // 4194304 B    (phase C)
    char* p = base + 201326592;
    float* xdbl = (float*)p;  p += 2162688;         // 16384x33
    p += 65536;                                     // (gap; was dlt)
    float* SP   = (float*)p;  p += 3145728;         // 16384x48
    float* G    = (float*)p;  p += 8192;            // 128x16
    float* F    = (float*)p;  p += 16777216;        // 128x2048x16
    float* H0   = (float*)p;  p += 16777216;        // 128x2048x16
    f16*   Wh   = (f16*)p;    p += 196608;          // 48x2048 f16 padded x_proj_w

    // fused dtype conversions (x, in_proj_w, padded x_proj_w)
    prep_k<<<2944, 256, 0, stream>>>(x, w_in, w_xp, xh, wih, Wh);

    // xz = x @ in_proj_w^T  (M=16384, N=4096, K=1024) — persistent, 4 tiles/blk
    gemm8p_pers<f16, 4><<<256, 512, 0, stream>>>(xh, wih, xzh, 4096, 1024, 1024, 4096);

    // depthwise conv + SiLU -> x_conv   (xh/wih dead; xch overlays them)
    conv_silu_k<<<2048, 256, 0, stream>>>(xzh, conv_w, conv_b, xch);

    // x_dbl = x_conv @ x_proj_w^T  (N=33 padded to 48) via MFMA
    xdbl_mfma_k<<<256, 256, 0, stream>>>(xch, Wh, xdbl);

    // per-(b,t) scan coefficients + chunk transitions (fused)
    spg_k<<<128, 128, 0, stream>>>(xdbl, A_log, SP, G);

    // chunked selective scan (T=128, 32 chunks/batch)
    scan1_k<<<1024, 256, 0, stream>>>(xch, SP, F);
    combine_k<<<512, 256, 0, stream>>>(F, G, H0);
    scan2_k<<<1024, 256, 0, stream>>>(xch, xzh, SP, H0, Dv, xzh);

    // convert out_proj_w late (xch dead; woh overlays region1)
    cvt_f16_k<<<2048, 256, 0, stream>>>(w_out, woh, 524288);

    // out = y @ out_proj_w^T  (M=16384, N=1024, K=2048, lda=4096, fp32 out)
    gemm8p_pers<float, 1><<<256, 512, 0, stream>>>(xzh, woh, (float*)d_out,
                                                   1024, 2048, 4096, 1024);
}

// Round 7
// 442.331 us; speedup vs baseline: 2.0625x; 1.0086x over previous
//
#include <hip/hip_runtime.h>
#include <hip/hip_fp16.h>

typedef _Float16 f16;
typedef _Float16 half8 __attribute__((ext_vector_type(8)));
typedef _Float16 half4v __attribute__((ext_vector_type(4)));
typedef float f32x4 __attribute__((ext_vector_type(4)));

#define AS1(p) ((const __attribute__((address_space(1))) void*)(p))
#define AS3(p) ((__attribute__((address_space(3))) void*)(p))

__device__ __forceinline__ void gload_lds16(const void* g, void* l) {
    __builtin_amdgcn_global_load_lds(AS1(g), AS3(l), 16, 0, 0);
}

// ---------------------------------------------------------------------------
// Fused input conversions: x, in_proj_w, out_proj_w (f32->f16) and
// x_proj_w (33x2048 -> zero-padded 48x2048 f16).  Grid 3456.
// ---------------------------------------------------------------------------
__global__ __launch_bounds__(256)
void prep_k(const float* __restrict__ x, const float* __restrict__ w_in,
            const float* __restrict__ w_xp, const float* __restrict__ w_out,
            f16* __restrict__ xh, f16* __restrict__ wih,
            f16* __restrict__ Wh, f16* __restrict__ woh) {
    int b = blockIdx.x;
    if (b < 2048) {
        for (int i = b * 256 + threadIdx.x; i < 4194304; i += 2048 * 256) {
            float4 v = ((const float4*)x)[i];
            half4v o; o[0] = (f16)v.x; o[1] = (f16)v.y; o[2] = (f16)v.z; o[3] = (f16)v.w;
            ((half4v*)xh)[i] = o;
        }
    } else if (b < 2560) {
        for (int i = (b - 2048) * 256 + threadIdx.x; i < 1048576; i += 512 * 256) {
            float4 v = ((const float4*)w_in)[i];
            half4v o; o[0] = (f16)v.x; o[1] = (f16)v.y; o[2] = (f16)v.z; o[3] = (f16)v.w;
            ((half4v*)wih)[i] = o;
        }
    } else if (b < 2944) {
        int idx = (b - 2560) * 256 + threadIdx.x;   // 0..98303
        int e = idx >> 11;
        int k = idx & 2047;
        Wh[idx] = (e < 33) ? (f16)w_xp[e * 2048 + k] : (f16)0.f;
    } else {
        for (int i = (b - 2944) * 256 + threadIdx.x; i < 524288; i += 512 * 256) {
            float4 v = ((const float4*)w_out)[i];
            half4v o; o[0] = (f16)v.x; o[1] = (f16)v.y; o[2] = (f16)v.z; o[3] = (f16)v.w;
            ((half4v*)woh)[i] = o;
        }
    }
}

// ===========================================================================
// Persistent 256x256 8-phase GEMM (T1+T2+T3+T4+T5), f16 MFMA 16x16x32.
// Supertile L2 mapping: s -> bm = 4*(s/(4*nTn)) + (s&3), bn = (s%(4*nTn))>>2.
// Each XCD's 32 concurrent tiles cover 4bm x 8bn (~6MB working set), and a
// persistent block's 4 tiles (delta-s = 32 = 0 mod 4) share the SAME bm ->
// A panel stays L2-hot across tiles.  Schedule identical to round 6
// (bridged prologue, vmcnt(6) pipeline; see round-4/5 derivations).
// ===========================================================================
__device__ __forceinline__ void stage_q(const f16* __restrict__ g, int ld,
                                        int row0, int gk, f16* q,
                                        int tid, int wave) {
#pragma unroll
    for (int rd = 0; rd < 2; ++rd) {
        int t = rd * 512 + tid;
        int r = t >> 2;                       // row 0..255
        int cu = (t & 3) ^ ((r >> 1) & 3);    // unswizzled chunk for this slot
        gload_lds16(g + (size_t)(row0 + r) * ld + gk + cu * 8,
                    q + rd * 4096 + wave * 512);   // wave-uniform linear dest
    }
}

#define PH(Q, KH, MH, LOADB, STAGE, WAITC)                                    \
  {                                                                           \
    half8 afr[4];                                                             \
    {                                                                         \
      const f16* aq = &lds[Q][0][KH][0];                                      \
      int ra = wm * 128 + (MH) * 64 + lr;                                     \
      afr[0] = *(const half8*)(aq + (ra +  0) * 32 + cofs);                   \
      afr[1] = *(const half8*)(aq + (ra + 16) * 32 + cofs);                   \
      afr[2] = *(const half8*)(aq + (ra + 32) * 32 + cofs);                   \
      afr[3] = *(const half8*)(aq + (ra + 48) * 32 + cofs);                   \
    }                                                                         \
    if (LOADB) {                                                              \
      const f16* bq = &lds[Q][1][KH][0];                                      \
      int rb = wn * 64 + lr;                                                  \
      bfr[0] = *(const half8*)(bq + (rb +  0) * 32 + cofs);                   \
      bfr[1] = *(const half8*)(bq + (rb + 16) * 32 + cofs);                   \
      bfr[2] = *(const half8*)(bq + (rb + 32) * 32 + cofs);                   \
      bfr[3] = *(const half8*)(bq + (rb + 48) * 32 + cofs);                   \
    }                                                                         \
    STAGE;                                                                    \
    __builtin_amdgcn_s_barrier();                                             \
    asm volatile("s_waitcnt lgkmcnt(0)" ::: "memory");                        \
    __builtin_amdgcn_sched_barrier(0);                                        \
    __builtin_amdgcn_s_setprio(1);                                            \
    _Pragma("unroll")                                                         \
    for (int f_ = 0; f_ < 4; ++f_)                                            \
      _Pragma("unroll")                                                       \
      for (int j_ = 0; j_ < 4; ++j_)                                          \
        acc[(MH) * 4 + f_][j_] = __builtin_amdgcn_mfma_f32_16x16x32_f16(      \
            afr[f_], bfr[j_], acc[(MH) * 4 + f_][j_], 0, 0, 0);               \
    __builtin_amdgcn_s_setprio(0);                                            \
    __builtin_amdgcn_sched_barrier(0);                                        \
    WAITC;                                                                    \
    __builtin_amdgcn_s_barrier();                                             \
  }

template <typename OutT, int NT>
__global__ __launch_bounds__(512, 2)
void gemm8p_pers(const f16* __restrict__ A, const f16* __restrict__ B,
                 OutT* __restrict__ C, int N, int K, int lda, int ldc) {
    __shared__ f16 lds[2][2][2][8192];   // [buf][A/B][kh][quarter] = 128 KiB

    int nTn = N >> 8;
    unsigned grid = gridDim.x;
    unsigned cpx = (grid * (unsigned)NT) >> 3;   // XCD chunk size (bijective)

    int tid = threadIdx.x;
    int wave = tid >> 6;
    int lane = tid & 63;
    int wm = wave >> 2;                   // 0..1
    int wn = wave & 3;                    // 0..3
    int lr = lane & 15;
    int cg = lane >> 4;                   // chunk group 0..3
    int cofs = ((cg ^ ((lr >> 1) & 3)) << 3);   // swizzled chunk offset (halfs)

    f32x4 acc[8][4];
#pragma unroll
    for (int i = 0; i < 8; ++i)
#pragma unroll
        for (int j = 0; j < 4; ++j) acc[i][j] = (f32x4){0.f, 0.f, 0.f, 0.f};
    half8 bfr[4];

    // tile j -> (bm,bn): XCD-chunked + 4x8 supertile (bm-fastest within group)
    auto tileMN = [&](int j, int& tm, int& tn) {
        unsigned o = blockIdx.x + grid * (unsigned)j;
        unsigned s = (o & 7u) * cpx + (o >> 3);
        unsigned gnn = (unsigned)(4 * nTn);
        unsigned g = s / gnn;
        unsigned r = s - g * gnn;
        tm = (int)(g * 4 + (r & 3u)) * 256;
        tn = (int)(r >> 2) * 256;
    };

    int bm, bn;
    tileMN(0, bm, bn);

    // prologue: kt0 fully (8 loads), kt1 B0/A0/B1 (6 loads); kt1 A1 at ph1
    stage_q(B, K,   bn, 0,  &lds[0][1][0][0], tid, wave);
    stage_q(A, lda, bm, 0,  &lds[0][0][0][0], tid, wave);
    stage_q(B, K,   bn, 32, &lds[0][1][1][0], tid, wave);
    stage_q(A, lda, bm, 32, &lds[0][0][1][0], tid, wave);
    stage_q(B, K,   bn, 64, &lds[1][1][0][0], tid, wave);
    stage_q(A, lda, bm, 64, &lds[1][0][0][0], tid, wave);
    stage_q(B, K,   bn, 96, &lds[1][1][1][0], tid, wave);
    asm volatile("s_waitcnt vmcnt(6)" ::: "memory");
    __builtin_amdgcn_s_barrier();

    int NI = K >> 7;                      // 2 K-tiles per iteration
    for (int j = 0; j < NT; ++j) {
        int bm2 = bm, bn2 = bn;
        if (j + 1 < NT) tileMN(j + 1, bm2, bn2);

        for (int it = 0; it < NI; ++it) {
            int gk = it << 7;
            bool lastIter = (it == NI - 1);
            bool fin = lastIter && (j + 1 == NT);   // absolute end
            int sbm = lastIter ? bm2 : bm;
            int sbn = lastIter ? bn2 : bn;
            int sgk = lastIter ? 0 : gk + 128;

            // --- K-tile kt0 (buf 0) ---
            PH(0, 0, 0, true,
               { stage_q(A, lda, bm, gk + 96, &lds[1][0][1][0], tid, wave); }, {});
            PH(0, 0, 1, false,
               { if (!fin) stage_q(B, K, sbn, sgk, &lds[0][1][0][0], tid, wave); }, {});
            PH(0, 1, 0, true,
               { if (!fin) stage_q(A, lda, sbm, sgk, &lds[0][0][0][0], tid, wave); }, {});
            PH(0, 1, 1, false,
               { if (!fin) stage_q(B, K, sbn, sgk + 32, &lds[0][1][1][0], tid, wave); },
               { if (fin) asm volatile("s_waitcnt vmcnt(0)" ::: "memory");
                 else     asm volatile("s_waitcnt vmcnt(6)" ::: "memory"); });
            // --- K-tile kt1 (buf 1) ---
            PH(1, 0, 0, true,
               { if (!fin) stage_q(A, lda, sbm, sgk + 32, &lds[0][0][1][0], tid, wave); }, {});
            PH(1, 0, 1, false,
               { if (!fin) stage_q(B, K, sbn, sgk + 64, &lds[1][1][0][0], tid, wave); }, {});
            PH(1, 1, 0, true,
               { if (!fin) stage_q(A, lda, sbm, sgk + 64, &lds[1][0][0][0], tid, wave); }, {});
            PH(1, 1, 1, false,
               { if (!fin) stage_q(B, K, sbn, sgk + 96, &lds[1][1][1][0], tid, wave); },
               { if (!fin) asm volatile("s_waitcnt vmcnt(6)" ::: "memory"); });
        }

        // epilogue tile j (registers only; no LDS -> safe vs in-flight stages)
        int orow0 = bm + wm * 128 + (lane >> 4) * 4;
        int ocol0 = bn + wn * 64 + lr;
#pragma unroll
        for (int mf = 0; mf < 8; ++mf)
#pragma unroll
            for (int nj = 0; nj < 4; ++nj)
#pragma unroll
                for (int r = 0; r < 4; ++r)
                    C[(size_t)(orow0 + mf * 16 + r) * ldc + (ocol0 + nj * 16)] =
                        (OutT)acc[mf][nj][r];
#pragma unroll
        for (int i2 = 0; i2 < 8; ++i2)
#pragma unroll
            for (int j2 = 0; j2 < 4; ++j2) acc[i2][j2] = (f32x4){0.f, 0.f, 0.f, 0.f};
        bm = bm2; bn = bn2;
    }
}

// ---------------------------------------------------------------------------
// x_dbl = x_conv @ Wh^T  (M=16384, N=48 padded from 33, K=2048) via MFMA.
// ---------------------------------------------------------------------------
__global__ __launch_bounds__(256, 2)
void xdbl_mfma_k(const f16* __restrict__ xc, const f16* __restrict__ Wh,
                 float* __restrict__ xdbl) {
    __shared__ f16 As[64 * 64];   // 8 KB
    __shared__ f16 Bs[48 * 64];   // 6 KB
    int bm = blockIdx.x * 64;
    int tid = threadIdx.x;
    int wave = tid >> 6;
    int lane = tid & 63;
    int srow = lane >> 3;
    int scol = (lane & 7) * 8;
    int lr = lane & 15;
    int lkh = (lane >> 4) * 8;

    f32x4 acc[3];
#pragma unroll
    for (int j = 0; j < 3; ++j) acc[j] = (f32x4){0.f, 0.f, 0.f, 0.f};

    for (int k0 = 0; k0 < 2048; k0 += 64) {
        __syncthreads();
#pragma unroll
        for (int i = 0; i < 2; ++i) {
            int slot = wave * 2 + i;
            gload_lds16(xc + (size_t)(bm + slot * 8 + srow) * 2048 + (k0 + scol),
                        As + slot * 512);
        }
        if (wave < 3) {
#pragma unroll
            for (int i = 0; i < 2; ++i) {
                int slot = wave * 2 + i;
                gload_lds16(Wh + (size_t)(slot * 8 + srow) * 2048 + (k0 + scol),
                            Bs + slot * 512);
            }
        }
        asm volatile("s_waitcnt vmcnt(0)" ::: "memory");
        __syncthreads();
#pragma unroll
        for (int kk = 0; kk < 2; ++kk) {
            half8 a = *(const half8*)(As + (wave * 16 + lr) * 64 + kk * 32 + lkh);
#pragma unroll
            for (int nj = 0; nj < 3; ++nj) {
                half8 b = *(const half8*)(Bs + (nj * 16 + lr) * 64 + kk * 32 + lkh);
                acc[nj] = __builtin_amdgcn_mfma_f32_16x16x32_f16(a, b, acc[nj], 0, 0, 0);
            }
        }
    }

    int orow0 = bm + wave * 16 + (lane >> 4) * 4;
#pragma unroll
    for (int nj = 0; nj < 3; ++nj) {
        int col = nj * 16 + lr;
        if (col < 33) {
#pragma unroll
            for (int r = 0; r < 4; ++r)
                xdbl[(size_t)(orow0 + r) * 33 + col] = acc[nj][r];
        }
    }
}

// ---------------------------------------------------------------------------
// Depthwise causal conv (k=4) + bias + SiLU.  8 rows/block, sliding window.
// ---------------------------------------------------------------------------
__global__ __launch_bounds__(256)
void conv_silu_k(const f16* __restrict__ xz, const float* __restrict__ cw,
                 const float* __restrict__ cb, f16* __restrict__ xc) {
    int r0 = blockIdx.x * 8;     // first output row (0..16376)
    int d0 = threadIdx.x << 3;   // 0..2040
    int l0 = r0 & 4095;          // position within batch

    const float4* cw4 = (const float4*)cw;
    float4 w[8];
    float bias[8];
#pragma unroll
    for (int e = 0; e < 8; ++e) { w[e] = cw4[d0 + e]; bias[e] = cb[d0 + e]; }

    half8 xv[11];
#pragma unroll
    for (int j = 0; j < 11; ++j) {
        if (l0 - 3 + j >= 0)
            xv[j] = *(const half8*)(xz + (size_t)(r0 - 3 + j) * 4096 + d0);
        else
            xv[j] = (half8){};
    }

#pragma unroll
    for (int rr = 0; rr < 8; ++rr) {
        float acc[8];
#pragma unroll
        for (int e = 0; e < 8; ++e) acc[e] = bias[e];
#pragma unroll
        for (int k = 0; k < 4; ++k) {
            half8 xk = xv[rr + k];
#pragma unroll
            for (int e = 0; e < 8; ++e) {
                float wj = (k == 0) ? w[e].x : (k == 1) ? w[e].y : (k == 2) ? w[e].z : w[e].w;
                acc[e] = fmaf((float)xk[e], wj, acc[e]);
            }
        }
        half8 out = {};
#pragma unroll
        for (int e = 0; e < 8; ++e) {
            float v = acc[e];
            out[e] = (f16)(v / (1.f + expf(-v)));
        }
        *(half8*)(xc + (size_t)(r0 + rr) * 2048 + d0) = out;
    }
}

// ---------------------------------------------------------------------------
// In-LDS SP build shared by scan1/scan2 (T=128):
// sp[t][48] = { exp(A_n*delta_t), delta_t*B_t, C_t } built from xdbl chunk.
// ---------------------------------------------------------------------------
__device__ __forceinline__ void build_sp(const float* __restrict__ xdbl,
                                         const float* __restrict__ alog,
                                         float* sp, float* red,
                                         int bc, int tid) {
    if (tid < 128) {
        int m = bc * 128 + tid;
        const float* row = xdbl + (size_t)m * 33;
        float v0 = row[0];
        float d = (v0 > 15.f) ? v0 : logf(1.f + expf(v0));  // softplus
        float* s = sp + tid * 48;
#pragma unroll
        for (int n = 0; n < 16; ++n) {
            float An = -expf(alog[n]);
            s[n] = expf(An * d);
            s[16 + n] = d * row[1 + n];
            s[32 + n] = row[17 + n];
        }
        if (red) red[tid] = d;
    }
}

// ---------------------------------------------------------------------------
// Scan pass 1 (T=128): SP built in LDS; local scan h0=0 -> F; dg==0 writes G.
// ---------------------------------------------------------------------------
__global__ __launch_bounds__(256)
void scan1_k(const f16* __restrict__ xc, const float* __restrict__ xdbl,
             const float* __restrict__ A_log,
             float* __restrict__ F, float* __restrict__ G) {
    __shared__ float sp[128 * 48];
    __shared__ float red[128];
    __shared__ float alog[16];
    int blk = blockIdx.x;
    int dg = blk & 7;
    int bc = blk >> 3;               // chunk 0..127
    int tid = threadIdx.x;
    int d = dg * 256 + tid;
    int mbase = bc * 128;

    if (tid < 16) alog[tid] = A_log[tid];
    __syncthreads();
    build_sp(xdbl, alog, sp, red, bc, tid);
    __syncthreads();
#pragma unroll
    for (int s2 = 64; s2 > 0; s2 >>= 1) {
        if (tid < s2) red[tid] += red[tid + s2];
        __syncthreads();
    }
    if (dg == 0 && tid < 16)
        G[bc * 16 + tid] = expf(-expf(alog[tid]) * red[0]);

    float h[16];
#pragma unroll
    for (int n = 0; n < 16; ++n) h[n] = 0.f;

#pragma unroll 2
    for (int tt = 0; tt < 128; ++tt) {
        const float* r = sp + tt * 48;
        float x = (float)xc[(size_t)(mbase + tt) * 2048 + d];
#pragma unroll
        for (int n = 0; n < 16; ++n) h[n] = fmaf(h[n], r[n], x * r[16 + n]);
    }
    size_t fb = ((size_t)bc * 2048 + d) * 16;
#pragma unroll
    for (int n = 0; n < 16; ++n) F[fb + n] = h[n];
}

// ---------------------------------------------------------------------------
// Combine: one thread per (b,d,n) scalar chain (131072 chains, 32 steps).
// ---------------------------------------------------------------------------
__global__ __launch_bounds__(256)
void combine_k(const float* __restrict__ F, const float* __restrict__ G,
               float* __restrict__ H0) {
    int gid = blockIdx.x * 256 + threadIdx.x;  // 0..131071
    int b = gid >> 15;
    int dn = gid & 32767;
    int n = dn & 15;
    float h = 0.f;
    for (int c = 0; c < 32; ++c) {
        int bc = b * 32 + c;
        size_t idx = (size_t)bc * 32768 + dn;
        H0[idx] = h;
        h = fmaf(G[bc * 16 + n], h, F[idx]);
    }
}

// ---------------------------------------------------------------------------
// Scan pass 2 (T=128): SP rebuilt in LDS; replay with h0; emit
// y = (scan_y + x*D) * silu(z) into dead x_inner columns of xz.
// ---------------------------------------------------------------------------
__global__ __launch_bounds__(256)
void scan2_k(const f16* __restrict__ xc, const f16* xz,
             const float* __restrict__ xdbl, const float* __restrict__ A_log,
             const float* __restrict__ H0, const float* __restrict__ Dv,
             f16* yout) {
    __shared__ float sp[128 * 48];
    __shared__ float alog[16];
    int blk = blockIdx.x;
    int dg = blk & 7;
    int bc = blk >> 3;
    int tid = threadIdx.x;
    int d = dg * 256 + tid;
    int mbase = bc * 128;

    if (tid < 16) alog[tid] = A_log[tid];
    __syncthreads();
    build_sp(xdbl, alog, sp, nullptr, bc, tid);
    __syncthreads();

    size_t fb = ((size_t)bc * 2048 + d) * 16;
    float h[16];
#pragma unroll
    for (int n = 0; n < 16; ++n) h[n] = H0[fb + n];
    float Dd = Dv[d];

#pragma unroll 2
    for (int tt = 0; tt < 128; ++tt) {
        const float* r = sp + tt * 48;
        size_t mrow = (size_t)(mbase + tt);
        float x = (float)xc[mrow * 2048 + d];
        float z = (float)xz[mrow * 4096 + 2048 + d];
        float y0 = 0.f, y1 = 0.f, y2 = 0.f, y3 = 0.f;
#pragma unroll
        for (int n = 0; n < 16; n += 4) {
            h[n]     = fmaf(h[n],     r[n],     x * r[16 + n]);
            h[n + 1] = fmaf(h[n + 1], r[n + 1], x * r[17 + n]);
            h[n + 2] = fmaf(h[n + 2], r[n + 2], x * r[18 + n]);
            h[n + 3] = fmaf(h[n + 3], r[n + 3], x * r[19 + n]);
            y0 = fmaf(h[n],     r[32 + n], y0);
            y1 = fmaf(h[n + 1], r[33 + n], y1);
            y2 = fmaf(h[n + 2], r[34 + n], y2);
            y3 = fmaf(h[n + 3], r[35 + n], y3);
        }
        float y = (y0 + y1) + (y2 + y3);
        float yf = fmaf(x, Dd, y);
        float sz = z / (1.f + expf(-z));
        yout[mrow * 4096 + d] = (f16)(yf * sz);
    }
}

// ---------------------------------------------------------------------------
// Workspace layout (aliased by lifetime; peak 241,442,816 B ~= 230 MiB):
//   [0,   134217728)  xzh  : f16 16384x4096 (x_inner|z; x_inner cols become y)
//   [134217728, +67108864) region1:
//        phase A (prep+GEMM1):  xh f16 16384x1024 @ +0, wih f16 4096x1024 @ +33554432
//        phase B (conv..scan2): xch f16 16384x2048 @ +0
//   [201326592, ...)  xdbl(2162688) G(8192) F(16777216) H0(16777216)
//                     Wh(196608) woh(4194304)   end = 241442816
// ---------------------------------------------------------------------------
extern "C" void kernel_launch(void* const* d_in, const int* in_sizes, int n_in,
                              void* d_out, int out_size, void* d_ws, size_t ws_size,
                              hipStream_t stream) {
    const float* x      = (const float*)d_in[0];
    const float* w_in   = (const float*)d_in[1];
    const float* conv_w = (const float*)d_in[2];
    const float* conv_b = (const float*)d_in[3];
    const float* w_xp   = (const float*)d_in[4];
    const float* A_log  = (const float*)d_in[5];
    const float* Dv     = (const float*)d_in[6];
    const float* w_out  = (const float*)d_in[7];

    char* base = (char*)d_ws;
    f16* xzh = (f16*)base;                          // 134217728 B
    char* r1 = base + 134217728;                    // 67108864 B shared region
    f16* xh  = (f16*)r1;                            // 33554432 B   (phase A)
    f16* wih = (f16*)(r1 + 33554432);               // 8388608 B    (phase A)
    f16* xch = (f16*)r1;                            // 67108864 B   (phase B)
    char* p = base + 201326592;
    float* xdbl = (float*)p;  p += 2162688;         // 16384x33
    float* G    = (float*)p;  p += 8192;            // 128x16
    float* F    = (float*)p;  p += 16777216;        // 128x2048x16
    float* H0   = (float*)p;  p += 16777216;        // 128x2048x16
    f16*   Wh   = (f16*)p;    p += 196608;          // 48x2048 f16 padded x_proj_w
    f16*   woh  = (f16*)p;    p += 4194304;         // 1024x2048 f16 out_proj_w

    // fused dtype conversions (x, in_proj_w, padded x_proj_w, out_proj_w)
    prep_k<<<3456, 256, 0, stream>>>(x, w_in, w_xp, w_out, xh, wih, Wh, woh);

    // xz = x @ in_proj_w^T  (M=16384, N=4096, K=1024) — persistent, 4 tiles/blk
    gemm8p_pers<f16, 4><<<256, 512, 0, stream>>>(xh, wih, xzh, 4096, 1024, 1024, 4096);

    // depthwise conv + SiLU -> x_conv   (xh/wih dead; xch overlays them)
    conv_silu_k<<<2048, 256, 0, stream>>>(xzh, conv_w, conv_b, xch);

    // x_dbl = x_conv @ x_proj_w^T  (N=33 padded to 48) via MFMA
    xdbl_mfma_k<<<256, 256, 0, stream>>>(xch, Wh, xdbl);

    // chunked selective scan (T=128, 32 chunks/batch; SP built in-LDS)
    scan1_k<<<1024, 256, 0, stream>>>(xch, xdbl, A_log, F, G);
    combine_k<<<512, 256, 0, stream>>>(F, G, H0);
    scan2_k<<<1024, 256, 0, stream>>>(xch, xzh, xdbl, A_log, H0, Dv, xzh);

    // out = y @ out_proj_w^T  (M=16384, N=1024, K=2048, lda=4096, fp32 out)
    gemm8p_pers<float, 1><<<256, 512, 0, stream>>>(xzh, woh, (float*)d_out,
                                                   1024, 2048, 4096, 1024);
}